// Round 16
// baseline (148.495 us; speedup 1.0000x reference)
//
#include <hip/hip_runtime.h>
#include <hip/hip_bf16.h>

// Shapes (fixed): B=2 T=1024 E=1024 H=8 W=31 D=63
// NTOK=2048, H*D=504 (pad 512), 3*H*D=1512 (pad 1536), 4E=4096

typedef __bf16 bf16;
typedef bf16 bf16x8 __attribute__((ext_vector_type(8)));
typedef bf16 bf16x4 __attribute__((ext_vector_type(4)));
typedef bf16 bf16x2 __attribute__((ext_vector_type(2)));
typedef float f32x4 __attribute__((ext_vector_type(4)));

__device__ __forceinline__ float rdlane(float x, int l)
{
    return __int_as_float(__builtin_amdgcn_readlane(__float_as_int(x), l));
}

// ---------------- fused rotary + layernorm1 --------------------------------
__global__ __launch_bounds__(256) void rotary_ln_kernel(
    const float* __restrict__ x, const float* __restrict__ w,
    const float* __restrict__ b, float* __restrict__ xr, bf16* __restrict__ Y)
{
    const int row = blockIdx.x;
    const int tid = threadIdx.x;
    float2 xv = *(const float2*)(x + (size_t)row * 512 + tid * 2);
    float i0 = exp2f(-(float)(2*tid)     * 0.025952563241307518f);
    float i1 = exp2f(-(float)(2*tid + 1) * 0.025952563241307518f);
    float a0 = xv.x * i0, a1 = xv.y * i1;
    float s0 = sinf(a0), s1 = sinf(a1);
    float c0 = cosf(a0), c1 = cosf(a1);
    *(float2*)(xr + (size_t)row * 1024 + tid*2)       = make_float2(s0, s1);
    *(float2*)(xr + (size_t)row * 1024 + 512 + tid*2) = make_float2(c0, c1);
    float s  = s0 + s1 + c0 + c1;
    float ss = s0*s0 + s1*s1 + c0*c0 + c1*c1;
    #pragma unroll
    for (int off = 32; off > 0; off >>= 1) {
        s  += __shfl_down(s, off);
        ss += __shfl_down(ss, off);
    }
    __shared__ float rs[4], rss[4];
    int wave = tid >> 6, lane = tid & 63;
    if (lane == 0) { rs[wave] = s; rss[wave] = ss; }
    __syncthreads();
    s  = rs[0] + rs[1] + rs[2] + rs[3];
    ss = rss[0] + rss[1] + rss[2] + rss[3];
    float mu   = s * (1.f / 1024.f);
    float var  = ss * (1.f / 1024.f) - mu * mu;
    float rstd = rsqrtf(var + 1e-5f);
    float2 w0 = *(const float2*)(w + tid*2);
    float2 b0 = *(const float2*)(b + tid*2);
    float2 w1 = *(const float2*)(w + 512 + tid*2);
    float2 b1 = *(const float2*)(b + 512 + tid*2);
    bf16x2 y0, y1;
    y0[0] = (bf16)((s0 - mu) * rstd * w0.x + b0.x);
    y0[1] = (bf16)((s1 - mu) * rstd * w0.y + b0.y);
    y1[0] = (bf16)((c0 - mu) * rstd * w1.x + b1.x);
    y1[1] = (bf16)((c1 - mu) * rstd * w1.y + b1.y);
    *(bf16x2*)(Y + (size_t)row * 1024 + tid*2)       = y0;
    *(bf16x2*)(Y + (size_t)row * 1024 + 512 + tid*2) = y1;
}

// ---------------- fused weight converts (fp32->bf16, zero-pad) + bias pad --
__device__ __forceinline__ void conv_chunk(
    const float* __restrict__ src, bf16* __restrict__ dst,
    int ci, int N, int K, int Kp)
{
    int kpc = Kp >> 3;
    int r  = ci / kpc;
    int kc = (ci - r * kpc) << 3;
    bf16x8 o;
    if (r < N && kc < K) {
        float4 f0 = *(const float4*)(src + (size_t)r * K + kc);
        float4 f1 = *(const float4*)(src + (size_t)r * K + kc + 4);
        o[0]=(bf16)f0.x; o[1]=(bf16)f0.y; o[2]=(bf16)f0.z; o[3]=(bf16)f0.w;
        o[4]=(bf16)f1.x; o[5]=(bf16)f1.y; o[6]=(bf16)f1.z; o[7]=(bf16)f1.w;
    } else {
        #pragma unroll
        for (int j = 0; j < 8; ++j) o[j] = (bf16)0.f;
    }
    *(bf16x8*)(dst + (size_t)r * Kp + kc) = o;
}

__global__ __launch_bounds__(256) void conv_all_kernel(
    const float* __restrict__ qkv_w, const float* __restrict__ proj_w,
    const float* __restrict__ fc_w,  const float* __restrict__ cproj_w,
    const float* __restrict__ qkv_b,
    bf16* __restrict__ wqkv, bf16* __restrict__ wproj,
    bf16* __restrict__ wfc,  bf16* __restrict__ wcproj,
    float* __restrict__ qkvb_p)
{
    if (blockIdx.x == 5120) {
        for (int i = threadIdx.x; i < 1536; i += 256)
            qkvb_p[i] = (i < 1512) ? qkv_b[i] : 0.f;
        return;
    }
    int idx = blockIdx.x * 256 + threadIdx.x;
    if      (idx < 196608)  conv_chunk(qkv_w,   wqkv,   idx,          1512, 1024, 1024);
    else if (idx < 262144)  conv_chunk(proj_w,  wproj,  idx - 196608, 1024,  504,  512);
    else if (idx < 786432)  conv_chunk(fc_w,    wfc,    idx - 262144, 4096, 1024, 1024);
    else                    conv_chunk(cproj_w, wcproj, idx - 786432, 1024, 4096, 4096);
}

// ---------------- helpers ---------------------------------------------------
template<int N> __device__ __forceinline__ void vmwait()
{
    if constexpr      (N==0) asm volatile("s_waitcnt vmcnt(0)" ::: "memory");
    else if constexpr (N==3) asm volatile("s_waitcnt vmcnt(3)" ::: "memory");
}
__device__ __forceinline__ void lgkmwait0()
{
    asm volatile("s_waitcnt lgkmcnt(0)" ::: "memory");
}
__device__ __forceinline__ void hw_barrier()
{
    asm volatile("s_barrier" ::: "memory");
}
__device__ __forceinline__ void gload16(const char* src, char* ldsdst)
{
    __builtin_amdgcn_global_load_lds(
        (const __attribute__((address_space(1))) void*)src,
        (__attribute__((address_space(3))) void*)ldsdst, 16, 0, 0);
}
__device__ __forceinline__ float gelu_exact(float v)
{
    return 0.5f * v * (1.f + erff(v * 0.70710678118654752f));
}

// ---------------- gemm11b: 128x128, 8 waves 2x4, 2-buf, 32 waves/CU --------
// Occupancy-max variant for split-K fc/cproj (grid 1024 WGs = 4 blk/CU):
// 2-buffer ping-pong, 32 KB LDS (cap 5), 512 thr (cap 4) -> 4 blk/CU x 8
// waves = 32 waves/CU (100%).  __syncthreads() per iter (gemm6-proven sync;
// the vmcnt drain is hidden by 8 waves/SIMD, m114).  Per-CU pipe model at 4
// blk: MFMA 1240 cyc > LDS 1024 cyc/iter -> MFMA-bound.  Zero-conflict
// swizzle (R12: SQ_LDS_BANK_CONFLICT=0) + bijective XCD swizzle.
// EPI: 3 = bf16 partial (no bias, z-strided)   [fc gelu moves to reducer]
template<int EPI>
__global__ __launch_bounds__(512, 8) void gemm11b_kernel(
    const bf16* __restrict__ A, const bf16* __restrict__ Wt,
    bf16* __restrict__ Cb, int N, int Kp, int ksplit)
{
    __shared__ __align__(16) char lds[2][16384];   // per buf: A 8KB | B 8KB

    const int tid  = threadIdx.x;       // 0..511
    const int w    = tid >> 6;
    const int lane = tid & 63;
    const int wm   = w >> 2;            // 0..1 : 64-row band
    const int wn   = w & 3;             // 0..3 : 32-col band
    const int rl   = lane & 15;
    const int slotR = lane >> 4;

    const int gx = gridDim.x, gy = gridDim.y;
    const int nwg = gx * gy * gridDim.z;
    const int chunk = nwg >> 3;
    int id = (blockIdx.z * gy + blockIdx.y) * gx + blockIdx.x;
    int sw = (id & 7) * chunk + (id >> 3);
    const int bx = sw % gx;
    const int t2 = sw / gx;
    const int by = t2 % gy;
    const int bz = t2 / gy;

    const int row0 = by * 128;
    const int col0 = bx * 128;
    const size_t strideBy = (size_t)Kp * 2;
    const size_t kz = (size_t)bz * ksplit * 2;
    const char* Abase = (const char*)A  + (size_t)row0 * strideBy + kz;
    const char* Wbase = (const char*)Wt + (size_t)col0 * strideBy + kz;

    // 1 A-chunk + 1 B-chunk per thread; pre-swizzled source (rule 21)
    const int r  = tid >> 2;
    const int s  = (tid & 3) ^ ((r >> 1) & 3);
    const size_t srcOff = (size_t)r * strideBy + (size_t)(s << 4);

    f32x4 acc[4][2] = {};

    auto STAGE = [&](int buf, int kt) {
        const char* ab = Abase + (size_t)kt * 64;
        const char* wb = Wbase + (size_t)kt * 64;
        gload16(ab + srcOff, &lds[buf][0]    + tid * 16);
        gload16(wb + srcOff, &lds[buf][8192] + tid * 16);
    };

    const int niter = ksplit >> 5;      // BK = 32; all call sites = 16
    STAGE(0, 0);
    __syncthreads();
    for (int kt = 0; kt < niter; ++kt) {
        if (kt + 1 < niter)
            STAGE((kt + 1) & 1, kt + 1);    // in flight during compute
        const char* base = lds[kt & 1];
        bf16x8 af[4], bfr[2];
        #pragma unroll
        for (int mi = 0; mi < 4; ++mi) {
            int rr = wm * 64 + mi * 16 + rl;
            af[mi] = *(const bf16x8*)
                (base + (rr << 6) + ((slotR ^ ((rr >> 1) & 3)) << 4));
        }
        #pragma unroll
        for (int nj = 0; nj < 2; ++nj) {
            int rr = wn * 32 + nj * 16 + rl;
            bfr[nj] = *(const bf16x8*)
                (base + 8192 + (rr << 6) + ((slotR ^ ((rr >> 1) & 3)) << 4));
        }
        __builtin_amdgcn_s_setprio(1);
        #pragma unroll
        for (int mi = 0; mi < 4; ++mi)
            #pragma unroll
            for (int nj = 0; nj < 2; ++nj)
                acc[mi][nj] = __builtin_amdgcn_mfma_f32_16x16x32_bf16(
                    af[mi], bfr[nj], acc[mi][nj], 0, 0, 0);
        __builtin_amdgcn_s_setprio(0);
        __syncthreads();                    // drain loads + protect ping-pong
    }

    // C/D layout: col = lane&15, row = (lane>>4)*4 + reg   [m89/m91]
    const int rq = (lane >> 4) * 4;
    bf16* Cbz = Cb + (size_t)bz * 2048 * N;
    #pragma unroll
    for (int mi = 0; mi < 4; ++mi) {
        #pragma unroll
        for (int rj = 0; rj < 4; ++rj) {
            int row = row0 + wm * 64 + mi * 16 + rq + rj;
            #pragma unroll
            for (int nj = 0; nj < 2; ++nj) {
                int col = col0 + wn * 32 + nj * 16 + rl;
                size_t off = (size_t)row * N + col;
                Cbz[off] = (bf16)acc[mi][nj][rj];
            }
        }
    }
}

// ---------------- gemm7: 64x128 tile, 4 waves, 3-buf (qkv / proj, R13) -----
template<int EPI>
__global__ __launch_bounds__(256, 4) void gemm7_kernel(
    const bf16* __restrict__ A, const bf16* __restrict__ Wt,
    const float* __restrict__ bias, bf16* __restrict__ Cb,
    int N, int Kp, int ksplit)
{
    __shared__ __align__(16) char lds[3][12288];   // per buf: A 4KB | B 8KB

    const int tid  = threadIdx.x;
    const int w    = tid >> 6;
    const int lane = tid & 63;

    const int gx = gridDim.x, gy = gridDim.y;
    const int nwg = gx * gy * gridDim.z;
    const int chunk = nwg >> 3;
    int id = (blockIdx.z * gy + blockIdx.y) * gx + blockIdx.x;
    int sw = (id & 7) * chunk + (id >> 3);
    const int bx = sw % gx;
    const int t2 = sw / gx;
    const int by = t2 % gy;
    const int bz = t2 / gy;

    const int row0 = by * 64;
    const int col0 = bx * 128;
    const int wr = (w >> 1) * 32;
    const int wc = (w & 1) * 64;
    const int rl = lane & 15;
    const int slotR = lane >> 4;

    const size_t strideBy = (size_t)Kp * 2;
    const size_t kz = (size_t)bz * ksplit * 2;
    const char* Abase = (const char*)A  + (size_t)row0 * strideBy + kz;
    const char* Wbase = (const char*)Wt + (size_t)col0 * strideBy + kz;

    const int arow = tid >> 2;
    const size_t srcA0 = (size_t)arow * strideBy
                       + (size_t)(((tid & 3) ^ ((arow >> 1) & 3)) << 4);
    size_t srcB[2];
    #pragma unroll
    for (int i = 0; i < 2; ++i) {
        int o = (i * 256 + tid) * 16;
        int rr = o >> 6;
        int ss = ((o & 63) >> 4) ^ ((rr >> 1) & 3);
        srcB[i] = (size_t)rr * strideBy + (size_t)(ss << 4);
    }

    f32x4 acc[2][4] = {};

    auto STAGE = [&](int buf, int kt) {
        const char* ab = Abase + (size_t)kt * 64;
        const char* wb = Wbase + (size_t)kt * 64;
        gload16(ab + srcA0, &lds[buf][0] + tid * 16);
        #pragma unroll
        for (int i = 0; i < 2; ++i)
            gload16(wb + srcB[i], &lds[buf][4096] + (i * 256 + tid) * 16);
    };

    const int niter = ksplit >> 5;      // BK = 32
    STAGE(0, 0);
    STAGE(1, 1);
    vmwait<3>();
    hw_barrier();

    int cur = 0, stg = 2;
    for (int kt = 0; kt < niter; ++kt) {
        if (kt + 2 < niter) STAGE(stg, kt + 2);
        const char* base = lds[cur];
        bf16x8 af[2], bfr[4];
        #pragma unroll
        for (int mi = 0; mi < 2; ++mi) {
            int rr = wr + mi * 16 + rl;
            af[mi] = *(const bf16x8*)
                (base + (rr << 6) + ((slotR ^ ((rr >> 1) & 3)) << 4));
        }
        #pragma unroll
        for (int nj = 0; nj < 4; ++nj) {
            int rr = wc + nj * 16 + rl;
            bfr[nj] = *(const bf16x8*)
                (base + 4096 + (rr << 6) + ((slotR ^ ((rr >> 1) & 3)) << 4));
        }
        __builtin_amdgcn_s_setprio(1);
        #pragma unroll
        for (int mi = 0; mi < 2; ++mi)
            #pragma unroll
            for (int nj = 0; nj < 4; ++nj)
                acc[mi][nj] = __builtin_amdgcn_mfma_f32_16x16x32_bf16(
                    af[mi], bfr[nj], acc[mi][nj], 0, 0, 0);
        __builtin_amdgcn_s_setprio(0);

        if (kt + 1 < niter) {
            lgkmwait0();
            if (kt + 2 < niter) vmwait<3>();
            else                vmwait<0>();
            hw_barrier();
        }
        cur = (cur == 2) ? 0 : cur + 1;
        stg = (stg == 2) ? 0 : stg + 1;
    }

    const int rq = (lane >> 4) * 4;
    bf16* Cbz = Cb;
    if (EPI == 3) Cbz += (size_t)bz * 2048 * N;
    #pragma unroll
    for (int mi = 0; mi < 2; ++mi) {
        #pragma unroll
        for (int rj = 0; rj < 4; ++rj) {
            int row = row0 + wr + mi*16 + rq + rj;
            #pragma unroll
            for (int nj = 0; nj < 4; ++nj) {
                int col = col0 + wc + nj*16 + rl;
                float c = acc[mi][nj][rj];
                size_t off = (size_t)row * N + col;
                if (EPI == 0)      Cbz[off] = (bf16)(c + bias[col]);
                else if (EPI == 1) Cbz[off] = (bf16)gelu_exact(c + bias[col]);
                else               Cbz[off] = (bf16)c;
            }
        }
    }
}

// ---------------- split-K reducer: out = R + bias + sum(parts), fp32 -------
template<int P>
__global__ __launch_bounds__(256) void reduce_kernel(
    const bf16* __restrict__ parts, const float* __restrict__ bias,
    const float* R, float* out)
{
    int row = blockIdx.x;
    int c = threadIdx.x * 4;
    size_t off = (size_t)row * 1024 + c;
    float4 bv = *(const float4*)(bias + c);
    float4 o = *(const float4*)(R + off);
    o.x += bv.x; o.y += bv.y; o.z += bv.z; o.w += bv.w;
    #pragma unroll
    for (int p = 0; p < P; ++p) {
        bf16x4 v = *(const bf16x4*)(parts + (size_t)p * 2048 * 1024 + off);
        o.x += (float)v[0]; o.y += (float)v[1];
        o.z += (float)v[2]; o.w += (float)v[3];
    }
    *(float4*)(out + off) = o;
}

// ---------------- fc split-K reducer: fc_act = gelu(p0+p1+bias), bf16 ------
__global__ __launch_bounds__(256) void reduce_gelu_kernel(
    const bf16* __restrict__ parts, const float* __restrict__ bias,
    bf16* __restrict__ out)
{
    size_t base = ((size_t)blockIdx.x * 256 + threadIdx.x) * 8;  // 2048*4096/8
    int col = (int)(base & 4095);
    bf16x8 p0 = *(const bf16x8*)(parts + base);
    bf16x8 p1 = *(const bf16x8*)(parts + (size_t)2048 * 4096 + base);
    float4 b0 = *(const float4*)(bias + col);
    float4 b1 = *(const float4*)(bias + col + 4);
    bf16x8 o;
    o[0] = (bf16)gelu_exact((float)p0[0] + (float)p1[0] + b0.x);
    o[1] = (bf16)gelu_exact((float)p0[1] + (float)p1[1] + b0.y);
    o[2] = (bf16)gelu_exact((float)p0[2] + (float)p1[2] + b0.z);
    o[3] = (bf16)gelu_exact((float)p0[3] + (float)p1[3] + b0.w);
    o[4] = (bf16)gelu_exact((float)p0[4] + (float)p1[4] + b1.x);
    o[5] = (bf16)gelu_exact((float)p0[5] + (float)p1[5] + b1.y);
    o[6] = (bf16)gelu_exact((float)p0[6] + (float)p1[6] + b1.z);
    o[7] = (bf16)gelu_exact((float)p0[7] + (float)p1[7] + b1.w);
    *(bf16x8*)(out + base) = o;
}

// ---------------- fused proj-reduce + LN2 ----------------------------------
__global__ __launch_bounds__(256) void reduceln_kernel(
    const bf16* __restrict__ parts, const float* __restrict__ bias,
    const float* __restrict__ R, const float* __restrict__ lnw,
    const float* __restrict__ lnb, float* __restrict__ out,
    bf16* __restrict__ Y)
{
    int row = blockIdx.x;
    int c = threadIdx.x * 4;
    size_t off = (size_t)row * 1024 + c;
    float4 bv = *(const float4*)(bias + c);
    float4 o  = *(const float4*)(R + off);
    o.x += bv.x; o.y += bv.y; o.z += bv.z; o.w += bv.w;
    #pragma unroll
    for (int p = 0; p < 2; ++p) {
        bf16x4 v = *(const bf16x4*)(parts + (size_t)p * 2048 * 1024 + off);
        o.x += (float)v[0]; o.y += (float)v[1];
        o.z += (float)v[2]; o.w += (float)v[3];
    }
    *(float4*)(out + off) = o;
    float s  = o.x + o.y + o.z + o.w;
    float ss = o.x*o.x + o.y*o.y + o.z*o.z + o.w*o.w;
    #pragma unroll
    for (int of = 32; of > 0; of >>= 1) {
        s  += __shfl_down(s, of);
        ss += __shfl_down(ss, of);
    }
    __shared__ float rs[4], rss[4];
    int wave = threadIdx.x >> 6, lane = threadIdx.x & 63;
    if (lane == 0) { rs[wave] = s; rss[wave] = ss; }
    __syncthreads();
    s  = rs[0] + rs[1] + rs[2] + rs[3];
    ss = rss[0] + rss[1] + rss[2] + rss[3];
    float mu  = s * (1.f / 1024.f);
    float var = ss * (1.f / 1024.f) - mu * mu;
    float rstd = rsqrtf(var + 1e-5f);
    float4 wv = *(const float4*)(lnw + c);
    float4 lb = *(const float4*)(lnb + c);
    bf16 y[4];
    y[0] = (bf16)((o.x - mu) * rstd * wv.x + lb.x);
    y[1] = (bf16)((o.y - mu) * rstd * wv.y + lb.y);
    y[2] = (bf16)((o.z - mu) * rstd * wv.z + lb.z);
    y[3] = (bf16)((o.w - mu) * rstd * wv.w + lb.w);
    *(uint2*)(Y + (size_t)row * 1024 + c) = *(uint2*)y;
}

// ---------------- windowed attention v3: 16 waves/block, exp2 tables -------
__global__ __launch_bounds__(1024) void attn3_kernel(
    const bf16* __restrict__ qkv, const float* __restrict__ rel_pos,
    bf16* __restrict__ outp)
{
    __shared__ float bR[4096];   // row-major bias*log2e, swizzled 16B slots
    __shared__ float bT[4096];   // transposed
    for (int i = threadIdx.x; i < 4096; i += 1024) {
        int d = i >> 6, v = i & 63;
        float val = (d < 63 && v < 63)
                  ? rel_pos[((d + 32) % 63) * 63 + v] * 1.4426950408889634f
                  : -1e30f;
        bR[(d << 6) + (((v >> 2) ^ (d & 15)) << 2) + (v & 3)] = val;
        bT[(v << 6) + (((d >> 2) ^ (v & 15)) << 2) + (d & 3)] = val;
    }
    __syncthreads();

    const int wave = threadIdx.x >> 6;
    const int lane = threadIdx.x & 63;
    const int tk  = blockIdx.x * 16 + wave;
    const int row = tk >> 3;
    const int h   = tk & 7;
    const bf16* base = qkv + (size_t)row * 1536 + h * 63;
    float q_own = 0.f, k_own = 0.f, v_own = 0.f;
    if (lane < 63) {
        q_own = (float)base[lane] * 1.4426950408889634f;
        k_own = (float)base[504 + lane];
        v_own = (float)base[1008 + lane];
    }

    const float* myT = bT + (lane << 6);
    const int sw = lane & 15;
    float z0 = 0.f, z1 = 0.f, z2 = 0.f, z3 = 0.f;
    #pragma unroll
    for (int g = 0; g < 16; ++g) {
        f32x4 bb = *(const f32x4*)(myT + ((g ^ sw) << 2));
        z0 += __builtin_amdgcn_exp2f(fmaf(rdlane(q_own, 4*g + 0), k_own, bb[0]));
        z1 += __builtin_amdgcn_exp2f(fmaf(rdlane(q_own, 4*g + 1), k_own, bb[1]));
        z2 += __builtin_amdgcn_exp2f(fmaf(rdlane(q_own, 4*g + 2), k_own, bb[2]));
        z3 += __builtin_amdgcn_exp2f(fmaf(rdlane(q_own, 4*g + 3), k_own, bb[3]));
    }
    float Z = (z0 + z1) + (z2 + z3);
    float w_own = (lane < 63) ? v_own / Z : 0.f;

    const float* myR = bR + (lane << 6);
    float a0 = 0.f, a1 = 0.f, a2 = 0.f, a3 = 0.f;
    #pragma unroll
    for (int g = 0; g < 16; ++g) {
        f32x4 bb = *(const f32x4*)(myR + ((g ^ sw) << 2));
        a0 = fmaf(__builtin_amdgcn_exp2f(fmaf(q_own, rdlane(k_own, 4*g + 0), bb[0])),
                  rdlane(w_own, 4*g + 0), a0);
        a1 = fmaf(__builtin_amdgcn_exp2f(fmaf(q_own, rdlane(k_own, 4*g + 1), bb[1])),
                  rdlane(w_own, 4*g + 1), a1);
        a2 = fmaf(__builtin_amdgcn_exp2f(fmaf(q_own, rdlane(k_own, 4*g + 2), bb[2])),
                  rdlane(w_own, 4*g + 2), a2);
        a3 = fmaf(__builtin_amdgcn_exp2f(fmaf(q_own, rdlane(k_own, 4*g + 3), bb[3])),
                  rdlane(w_own, 4*g + 3), a3);
    }
    float acc = (a0 + a1) + (a2 + a3);

    if (lane < 63)
        outp[(size_t)row * 512 + h*63 + lane] = (bf16)acc;
    if (h == 7 && lane == 63) {
        #pragma unroll
        for (int j = 0; j < 8; ++j)
            outp[(size_t)row * 512 + 504 + j] = (bf16)0.f;
    }
}

extern "C" void kernel_launch(void* const* d_in, const int* in_sizes, int n_in,
                              void* d_out, int out_size, void* d_ws, size_t ws_size,
                              hipStream_t stream)
{
    const float* x       = (const float*)d_in[0];
    const float* ln1_w   = (const float*)d_in[1];
    const float* ln1_b   = (const float*)d_in[2];
    const float* qkv_w   = (const float*)d_in[3];
    const float* qkv_b   = (const float*)d_in[4];
    const float* rel_pos = (const float*)d_in[5];
    const float* proj_w  = (const float*)d_in[6];
    const float* proj_b  = (const float*)d_in[7];
    const float* ln2_w   = (const float*)d_in[8];
    const float* ln2_b   = (const float*)d_in[9];
    const float* fc_w    = (const float*)d_in[10];
    const float* fc_b    = (const float*)d_in[11];
    const float* cproj_w = (const float*)d_in[12];
    const float* cproj_b = (const float*)d_in[13];
    float* out = (float*)d_out;

    // ---- workspace layout (bytes), ws_size = 256 MiB (measured via fill) --
    char* p = (char*)d_ws;
    float* xr      = (float*)p;            p += (size_t)2048*1024*4;   // 8 MB
    bf16*  h_bf    = (bf16*)p;             p += (size_t)2048*1024*2;   // 4 MB
    bf16*  wqkv    = (bf16*)p;             p += (size_t)1536*1024*2;   // 3 MB
    bf16*  wproj   = (bf16*)p;             p += (size_t)1024*512*2;    // 1 MB
    bf16*  wfc     = (bf16*)p;             p += (size_t)4096*1024*2;   // 8 MB
    bf16*  wcproj  = (bf16*)p;             p += (size_t)1024*4096*2;   // 8 MB
    float* qkvb_p  = (float*)p;            p += 8192;                  // 6 KB
    bf16*  attn_bf = (bf16*)p;             p += (size_t)2048*512*2;    // 2 MB
    bf16*  qkvb    = (bf16*)p;             p += (size_t)2048*1536*2;   // 6 MB
    bf16*  fc_act  = (bf16*)p;             p += (size_t)2048*4096*2;   // 16 MB
    bf16*  proj_part = qkvb;               // reuse qkvb (dead after attn)
    bf16*  fc_part = (bf16*)p;             p += (size_t)2*2048*4096*2; // 32 MB
    bf16*  cp_part = (bf16*)p;             p += (size_t)8*2048*1024*2; // 32 MB
    // total ~112 MB < 256 MiB

    conv_all_kernel<<<5121, 256, 0, stream>>>(qkv_w, proj_w, fc_w, cproj_w, qkv_b,
                                              wqkv, wproj, wfc, wcproj, qkvb_p);
    rotary_ln_kernel<<<2048, 256, 0, stream>>>(x, ln1_w, ln1_b, xr, h_bf);
    // qkv: M=2048 N=1536 K=1024 -> 12x32 = 384 WGs (gemm7, R13-proven)
    gemm7_kernel<0><<<dim3(12,32,1), 256, 0, stream>>>(h_bf, wqkv, qkvb_p,
                                                       qkvb, 1536, 1024, 1024);
    attn3_kernel<<<1024, 1024, 0, stream>>>(qkvb, rel_pos, attn_bf);
    // proj: M=2048 N=1024 K=512, split-K2 -> 8x32x2 = 512 WGs
    gemm7_kernel<3><<<dim3(8,32,2), 256, 0, stream>>>(attn_bf, wproj, nullptr,
                                                      proj_part, 1024, 512, 256);
    reduceln_kernel<<<2048, 256, 0, stream>>>(proj_part, proj_b, xr,
                                              ln2_w, ln2_b, out, h_bf);
    // fc: M=2048 N=4096 K=1024, split-K2 -> gemm11b 32x16x2 = 1024 WGs
    // (4 blk/CU x 8 waves = 32 waves/CU); gelu applied in the reducer
    gemm11b_kernel<3><<<dim3(32,16,2), 512, 0, stream>>>(h_bf, wfc,
                                                         fc_part, 4096, 1024, 512);
    reduce_gelu_kernel<<<4096, 256, 0, stream>>>(fc_part, fc_b, fc_act);
    // cproj: M=2048 N=1024 K=4096, split-K8 -> gemm11b 8x16x8 = 1024 WGs
    gemm11b_kernel<3><<<dim3(8,16,8), 512, 0, stream>>>(fc_act, wcproj,
                                                        cp_part, 1024, 4096, 512);
    reduce_kernel<8><<<2048, 256, 0, stream>>>(cp_part, cproj_b, out, out);
}

// Round 17
// 132.649 us; speedup vs baseline: 1.1195x; 1.1195x over previous
//
#include <hip/hip_runtime.h>
#include <hip/hip_bf16.h>

// Shapes (fixed): B=2 T=1024 E=1024 H=8 W=31 D=63
// NTOK=2048, H*D=504 (pad 512), 3*H*D=1512 (pad 1536), 4E=4096

typedef __bf16 bf16;
typedef bf16 bf16x8 __attribute__((ext_vector_type(8)));
typedef bf16 bf16x4 __attribute__((ext_vector_type(4)));
typedef bf16 bf16x2 __attribute__((ext_vector_type(2)));
typedef float f32x4 __attribute__((ext_vector_type(4)));

__device__ __forceinline__ float rdlane(float x, int l)
{
    return __int_as_float(__builtin_amdgcn_readlane(__float_as_int(x), l));
}

// ---------------- fused rotary + layernorm1 (xr stored bf16) ---------------
__global__ __launch_bounds__(256) void rotary_ln_kernel(
    const float* __restrict__ x, const float* __restrict__ w,
    const float* __restrict__ b, bf16* __restrict__ xr, bf16* __restrict__ Y)
{
    const int row = blockIdx.x;
    const int tid = threadIdx.x;
    float2 xv = *(const float2*)(x + (size_t)row * 512 + tid * 2);
    float i0 = exp2f(-(float)(2*tid)     * 0.025952563241307518f);
    float i1 = exp2f(-(float)(2*tid + 1) * 0.025952563241307518f);
    float a0 = xv.x * i0, a1 = xv.y * i1;
    float s0 = sinf(a0), s1 = sinf(a1);
    float c0 = cosf(a0), c1 = cosf(a1);
    bf16x2 xs, xc;
    xs[0] = (bf16)s0; xs[1] = (bf16)s1;
    xc[0] = (bf16)c0; xc[1] = (bf16)c1;
    *(bf16x2*)(xr + (size_t)row * 1024 + tid*2)       = xs;
    *(bf16x2*)(xr + (size_t)row * 1024 + 512 + tid*2) = xc;
    float s  = s0 + s1 + c0 + c1;
    float ss = s0*s0 + s1*s1 + c0*c0 + c1*c1;
    #pragma unroll
    for (int off = 32; off > 0; off >>= 1) {
        s  += __shfl_down(s, off);
        ss += __shfl_down(ss, off);
    }
    __shared__ float rs[4], rss[4];
    int wave = tid >> 6, lane = tid & 63;
    if (lane == 0) { rs[wave] = s; rss[wave] = ss; }
    __syncthreads();
    s  = rs[0] + rs[1] + rs[2] + rs[3];
    ss = rss[0] + rss[1] + rss[2] + rss[3];
    float mu   = s * (1.f / 1024.f);
    float var  = ss * (1.f / 1024.f) - mu * mu;
    float rstd = rsqrtf(var + 1e-5f);
    float2 w0 = *(const float2*)(w + tid*2);
    float2 b0 = *(const float2*)(b + tid*2);
    float2 w1 = *(const float2*)(w + 512 + tid*2);
    float2 b1 = *(const float2*)(b + 512 + tid*2);
    bf16x2 y0, y1;
    y0[0] = (bf16)((s0 - mu) * rstd * w0.x + b0.x);
    y0[1] = (bf16)((s1 - mu) * rstd * w0.y + b0.y);
    y1[0] = (bf16)((c0 - mu) * rstd * w1.x + b1.x);
    y1[1] = (bf16)((c1 - mu) * rstd * w1.y + b1.y);
    *(bf16x2*)(Y + (size_t)row * 1024 + tid*2)       = y0;
    *(bf16x2*)(Y + (size_t)row * 1024 + 512 + tid*2) = y1;
}

// ---------------- fused weight converts (fp32->bf16, zero-pad) + bias pad --
__device__ __forceinline__ void conv_chunk(
    const float* __restrict__ src, bf16* __restrict__ dst,
    int ci, int N, int K, int Kp)
{
    int kpc = Kp >> 3;
    int r  = ci / kpc;
    int kc = (ci - r * kpc) << 3;
    bf16x8 o;
    if (r < N && kc < K) {
        float4 f0 = *(const float4*)(src + (size_t)r * K + kc);
        float4 f1 = *(const float4*)(src + (size_t)r * K + kc + 4);
        o[0]=(bf16)f0.x; o[1]=(bf16)f0.y; o[2]=(bf16)f0.z; o[3]=(bf16)f0.w;
        o[4]=(bf16)f1.x; o[5]=(bf16)f1.y; o[6]=(bf16)f1.z; o[7]=(bf16)f1.w;
    } else {
        #pragma unroll
        for (int j = 0; j < 8; ++j) o[j] = (bf16)0.f;
    }
    *(bf16x8*)(dst + (size_t)r * Kp + kc) = o;
}

__global__ __launch_bounds__(256) void conv_all_kernel(
    const float* __restrict__ qkv_w, const float* __restrict__ proj_w,
    const float* __restrict__ fc_w,  const float* __restrict__ cproj_w,
    const float* __restrict__ qkv_b,
    bf16* __restrict__ wqkv, bf16* __restrict__ wproj,
    bf16* __restrict__ wfc,  bf16* __restrict__ wcproj,
    float* __restrict__ qkvb_p)
{
    if (blockIdx.x == 5120) {
        for (int i = threadIdx.x; i < 1536; i += 256)
            qkvb_p[i] = (i < 1512) ? qkv_b[i] : 0.f;
        return;
    }
    int idx = blockIdx.x * 256 + threadIdx.x;
    if      (idx < 196608)  conv_chunk(qkv_w,   wqkv,   idx,          1512, 1024, 1024);
    else if (idx < 262144)  conv_chunk(proj_w,  wproj,  idx - 196608, 1024,  504,  512);
    else if (idx < 786432)  conv_chunk(fc_w,    wfc,    idx - 262144, 4096, 1024, 1024);
    else                    conv_chunk(cproj_w, wcproj, idx - 786432, 1024, 4096, 4096);
}

// ---------------- helpers ---------------------------------------------------
template<int N> __device__ __forceinline__ void vmwait()
{
    if constexpr      (N==0) asm volatile("s_waitcnt vmcnt(0)" ::: "memory");
    else if constexpr (N==2) asm volatile("s_waitcnt vmcnt(2)" ::: "memory");
    else if constexpr (N==3) asm volatile("s_waitcnt vmcnt(3)" ::: "memory");
}
__device__ __forceinline__ void lgkmwait0()
{
    asm volatile("s_waitcnt lgkmcnt(0)" ::: "memory");
}
__device__ __forceinline__ void hw_barrier()
{
    asm volatile("s_barrier" ::: "memory");
}
__device__ __forceinline__ void gload16(const char* src, char* ldsdst)
{
    __builtin_amdgcn_global_load_lds(
        (const __attribute__((address_space(1))) void*)src,
        (__attribute__((address_space(3))) void*)ldsdst, 16, 0, 0);
}
__device__ __forceinline__ float gelu_exact(float v)
{
    return 0.5f * v * (1.f + erff(v * 0.70710678118654752f));
}

// ---------------- gemm11: 128x128 tile, 8 waves 2x4, per-wave 64x32 --------
// R15 best-known for fc/cproj: 512 WGs -> 2 blk/CU x 8 waves = 16 waves/CU
// (4/SIMD).  BK=32, 3-buf ring 48KB, counted vmcnt(2), single barrier/iter,
// zero-conflict swizzle (R12: SQ_LDS_BANK_CONFLICT=0) + XCD swizzle.
// EPI: 1 gelu->bf16 (+bias), 3 bf16 partial (z-strided)
template<int EPI>
__global__ __launch_bounds__(512, 4) void gemm11_kernel(
    const bf16* __restrict__ A, const bf16* __restrict__ Wt,
    const float* __restrict__ bias, bf16* __restrict__ Cb,
    int N, int Kp, int ksplit)
{
    __shared__ __align__(16) char lds[3][16384];   // per buf: A 8KB | B 8KB

    const int tid  = threadIdx.x;       // 0..511
    const int w    = tid >> 6;
    const int lane = tid & 63;
    const int wm   = w >> 2;            // 0..1 : 64-row band
    const int wn   = w & 3;             // 0..3 : 32-col band
    const int rl   = lane & 15;
    const int slotR = lane >> 4;

    const int gx = gridDim.x, gy = gridDim.y;
    const int nwg = gx * gy * gridDim.z;
    const int chunk = nwg >> 3;
    int id = (blockIdx.z * gy + blockIdx.y) * gx + blockIdx.x;
    int sw = (id & 7) * chunk + (id >> 3);
    const int bx = sw % gx;
    const int t2 = sw / gx;
    const int by = t2 % gy;
    const int bz = t2 / gy;

    const int row0 = by * 128;
    const int col0 = bx * 128;
    const size_t strideBy = (size_t)Kp * 2;
    const size_t kz = (size_t)bz * ksplit * 2;
    const char* Abase = (const char*)A  + (size_t)row0 * strideBy + kz;
    const char* Wbase = (const char*)Wt + (size_t)col0 * strideBy + kz;

    // 1 A-chunk + 1 B-chunk per thread; pre-swizzled source (rule 21)
    const int r  = tid >> 2;
    const int s  = (tid & 3) ^ ((r >> 1) & 3);
    const size_t srcOff = (size_t)r * strideBy + (size_t)(s << 4);

    f32x4 acc[4][2] = {};

    auto STAGE = [&](int buf, int kt) {
        const char* ab = Abase + (size_t)kt * 64;
        const char* wb = Wbase + (size_t)kt * 64;
        gload16(ab + srcOff, &lds[buf][0]    + tid * 16);
        gload16(wb + srcOff, &lds[buf][8192] + tid * 16);
    };

    const int niter = ksplit >> 5;      // BK = 32; all call sites = 32
    STAGE(0, 0);
    STAGE(1, 1);
    vmwait<2>();                        // tile 0 landed; tile 1 in flight
    hw_barrier();

    for (int kt = 0; kt < niter; ++kt) {
        if (kt + 2 < niter) STAGE((kt + 2) % 3, kt + 2);
        const char* base = lds[kt % 3];
        bf16x8 af[4], bfr[2];
        #pragma unroll
        for (int mi = 0; mi < 4; ++mi) {
            int rr = wm * 64 + mi * 16 + rl;
            af[mi] = *(const bf16x8*)
                (base + (rr << 6) + ((slotR ^ ((rr >> 1) & 3)) << 4));
        }
        #pragma unroll
        for (int nj = 0; nj < 2; ++nj) {
            int rr = wn * 32 + nj * 16 + rl;
            bfr[nj] = *(const bf16x8*)
                (base + 8192 + (rr << 6) + ((slotR ^ ((rr >> 1) & 3)) << 4));
        }
        lgkmwait0();                    // own reads done (WAR cert pre-barrier)
        __builtin_amdgcn_s_setprio(1);
        #pragma unroll
        for (int mi = 0; mi < 4; ++mi)
            #pragma unroll
            for (int nj = 0; nj < 2; ++nj)
                acc[mi][nj] = __builtin_amdgcn_mfma_f32_16x16x32_bf16(
                    af[mi], bfr[nj], acc[mi][nj], 0, 0, 0);
        __builtin_amdgcn_s_setprio(0);

        if (kt + 1 < niter) {
            if (kt + 2 < niter) vmwait<2>();    // (t+1) landed; (t+2) flying
            else                vmwait<0>();    // tail
            hw_barrier();                       // collective certification
        }
    }

    // C/D layout: col = lane&15, row = (lane>>4)*4 + reg   [m89/m91]
    const int rq = (lane >> 4) * 4;
    bf16* Cbz = Cb;
    if (EPI == 3) Cbz += (size_t)bz * 2048 * N;
    #pragma unroll
    for (int mi = 0; mi < 4; ++mi) {
        #pragma unroll
        for (int rj = 0; rj < 4; ++rj) {
            int row = row0 + wm * 64 + mi * 16 + rq + rj;
            #pragma unroll
            for (int nj = 0; nj < 2; ++nj) {
                int col = col0 + wn * 32 + nj * 16 + rl;
                float c = acc[mi][nj][rj];
                size_t off = (size_t)row * N + col;
                if (EPI == 1) Cbz[off] = (bf16)gelu_exact(c + bias[col]);
                else          Cbz[off] = (bf16)c;
            }
        }
    }
}

// ---------------- gemm7: 64x128 tile, 4 waves, 3-buf (qkv / proj, R13) -----
template<int EPI>
__global__ __launch_bounds__(256, 4) void gemm7_kernel(
    const bf16* __restrict__ A, const bf16* __restrict__ Wt,
    const float* __restrict__ bias, bf16* __restrict__ Cb,
    int N, int Kp, int ksplit)
{
    __shared__ __align__(16) char lds[3][12288];   // per buf: A 4KB | B 8KB

    const int tid  = threadIdx.x;
    const int w    = tid >> 6;
    const int lane = tid & 63;

    const int gx = gridDim.x, gy = gridDim.y;
    const int nwg = gx * gy * gridDim.z;
    const int chunk = nwg >> 3;
    int id = (blockIdx.z * gy + blockIdx.y) * gx + blockIdx.x;
    int sw = (id & 7) * chunk + (id >> 3);
    const int bx = sw % gx;
    const int t2 = sw / gx;
    const int by = t2 % gy;
    const int bz = t2 / gy;

    const int row0 = by * 64;
    const int col0 = bx * 128;
    const int wr = (w >> 1) * 32;
    const int wc = (w & 1) * 64;
    const int rl = lane & 15;
    const int slotR = lane >> 4;

    const size_t strideBy = (size_t)Kp * 2;
    const size_t kz = (size_t)bz * ksplit * 2;
    const char* Abase = (const char*)A  + (size_t)row0 * strideBy + kz;
    const char* Wbase = (const char*)Wt + (size_t)col0 * strideBy + kz;

    const int arow = tid >> 2;
    const size_t srcA0 = (size_t)arow * strideBy
                       + (size_t)(((tid & 3) ^ ((arow >> 1) & 3)) << 4);
    size_t srcB[2];
    #pragma unroll
    for (int i = 0; i < 2; ++i) {
        int o = (i * 256 + tid) * 16;
        int rr = o >> 6;
        int ss = ((o & 63) >> 4) ^ ((rr >> 1) & 3);
        srcB[i] = (size_t)rr * strideBy + (size_t)(ss << 4);
    }

    f32x4 acc[2][4] = {};

    auto STAGE = [&](int buf, int kt) {
        const char* ab = Abase + (size_t)kt * 64;
        const char* wb = Wbase + (size_t)kt * 64;
        gload16(ab + srcA0, &lds[buf][0] + tid * 16);
        #pragma unroll
        for (int i = 0; i < 2; ++i)
            gload16(wb + srcB[i], &lds[buf][4096] + (i * 256 + tid) * 16);
    };

    const int niter = ksplit >> 5;      // BK = 32
    STAGE(0, 0);
    STAGE(1, 1);
    vmwait<3>();
    hw_barrier();

    int cur = 0, stg = 2;
    for (int kt = 0; kt < niter; ++kt) {
        if (kt + 2 < niter) STAGE(stg, kt + 2);
        const char* base = lds[cur];
        bf16x8 af[2], bfr[4];
        #pragma unroll
        for (int mi = 0; mi < 2; ++mi) {
            int rr = wr + mi * 16 + rl;
            af[mi] = *(const bf16x8*)
                (base + (rr << 6) + ((slotR ^ ((rr >> 1) & 3)) << 4));
        }
        #pragma unroll
        for (int nj = 0; nj < 4; ++nj) {
            int rr = wc + nj * 16 + rl;
            bfr[nj] = *(const bf16x8*)
                (base + 4096 + (rr << 6) + ((slotR ^ ((rr >> 1) & 3)) << 4));
        }
        __builtin_amdgcn_s_setprio(1);
        #pragma unroll
        for (int mi = 0; mi < 2; ++mi)
            #pragma unroll
            for (int nj = 0; nj < 4; ++nj)
                acc[mi][nj] = __builtin_amdgcn_mfma_f32_16x16x32_bf16(
                    af[mi], bfr[nj], acc[mi][nj], 0, 0, 0);
        __builtin_amdgcn_s_setprio(0);

        if (kt + 1 < niter) {
            lgkmwait0();
            if (kt + 2 < niter) vmwait<3>();
            else                vmwait<0>();
            hw_barrier();
        }
        cur = (cur == 2) ? 0 : cur + 1;
        stg = (stg == 2) ? 0 : stg + 1;
    }

    const int rq = (lane >> 4) * 4;
    bf16* Cbz = Cb;
    if (EPI == 3) Cbz += (size_t)bz * 2048 * N;
    #pragma unroll
    for (int mi = 0; mi < 2; ++mi) {
        #pragma unroll
        for (int rj = 0; rj < 4; ++rj) {
            int row = row0 + wr + mi*16 + rq + rj;
            #pragma unroll
            for (int nj = 0; nj < 4; ++nj) {
                int col = col0 + wc + nj*16 + rl;
                float c = acc[mi][nj][rj];
                size_t off = (size_t)row * N + col;
                if (EPI == 0)      Cbz[off] = (bf16)(c + bias[col]);
                else if (EPI == 1) Cbz[off] = (bf16)gelu_exact(c + bias[col]);
                else               Cbz[off] = (bf16)c;
            }
        }
    }
}

// ---------------- split-K reducer: out = R + bias + sum(parts) -------------
template<int P>
__global__ __launch_bounds__(256) void reduce_kernel(
    const bf16* __restrict__ parts, const float* __restrict__ bias,
    const float* R, float* out)
{
    int row = blockIdx.x;
    int c = threadIdx.x * 4;
    size_t off = (size_t)row * 1024 + c;
    float4 bv = *(const float4*)(bias + c);
    float4 o = *(const float4*)(R + off);
    o.x += bv.x; o.y += bv.y; o.z += bv.z; o.w += bv.w;
    #pragma unroll
    for (int p = 0; p < P; ++p) {
        bf16x4 v = *(const bf16x4*)(parts + (size_t)p * 2048 * 1024 + off);
        o.x += (float)v[0]; o.y += (float)v[1];
        o.z += (float)v[2]; o.w += (float)v[3];
    }
    *(float4*)(out + off) = o;
}

// ---------------- fused proj-reduce + LN2 (R is bf16 xr) -------------------
__global__ __launch_bounds__(256) void reduceln_kernel(
    const bf16* __restrict__ parts, const float* __restrict__ bias,
    const bf16* __restrict__ R, const float* __restrict__ lnw,
    const float* __restrict__ lnb, float* __restrict__ out,
    bf16* __restrict__ Y)
{
    int row = blockIdx.x;
    int c = threadIdx.x * 4;
    size_t off = (size_t)row * 1024 + c;
    float4 bv = *(const float4*)(bias + c);
    bf16x4 rv = *(const bf16x4*)(R + off);
    float4 o;
    o.x = (float)rv[0] + bv.x;
    o.y = (float)rv[1] + bv.y;
    o.z = (float)rv[2] + bv.z;
    o.w = (float)rv[3] + bv.w;
    #pragma unroll
    for (int p = 0; p < 2; ++p) {
        bf16x4 v = *(const bf16x4*)(parts + (size_t)p * 2048 * 1024 + off);
        o.x += (float)v[0]; o.y += (float)v[1];
        o.z += (float)v[2]; o.w += (float)v[3];
    }
    *(float4*)(out + off) = o;
    float s  = o.x + o.y + o.z + o.w;
    float ss = o.x*o.x + o.y*o.y + o.z*o.z + o.w*o.w;
    #pragma unroll
    for (int of = 32; of > 0; of >>= 1) {
        s  += __shfl_down(s, of);
        ss += __shfl_down(ss, of);
    }
    __shared__ float rs[4], rss[4];
    int wave = threadIdx.x >> 6, lane = threadIdx.x & 63;
    if (lane == 0) { rs[wave] = s; rss[wave] = ss; }
    __syncthreads();
    s  = rs[0] + rs[1] + rs[2] + rs[3];
    ss = rss[0] + rss[1] + rss[2] + rss[3];
    float mu  = s * (1.f / 1024.f);
    float var = ss * (1.f / 1024.f) - mu * mu;
    float rstd = rsqrtf(var + 1e-5f);
    float4 wv = *(const float4*)(lnw + c);
    float4 lb = *(const float4*)(lnb + c);
    bf16 y[4];
    y[0] = (bf16)((o.x - mu) * rstd * wv.x + lb.x);
    y[1] = (bf16)((o.y - mu) * rstd * wv.y + lb.y);
    y[2] = (bf16)((o.z - mu) * rstd * wv.z + lb.z);
    y[3] = (bf16)((o.w - mu) * rstd * wv.w + lb.w);
    *(uint2*)(Y + (size_t)row * 1024 + c) = *(uint2*)y;
}

// ---------------- windowed attention v3: 16 waves/block, exp2 tables -------
__global__ __launch_bounds__(1024) void attn3_kernel(
    const bf16* __restrict__ qkv, const float* __restrict__ rel_pos,
    bf16* __restrict__ outp)
{
    __shared__ float bR[4096];   // row-major bias*log2e, swizzled 16B slots
    __shared__ float bT[4096];   // transposed
    for (int i = threadIdx.x; i < 4096; i += 1024) {
        int d = i >> 6, v = i & 63;
        float val = (d < 63 && v < 63)
                  ? rel_pos[((d + 32) % 63) * 63 + v] * 1.4426950408889634f
                  : -1e30f;
        bR[(d << 6) + (((v >> 2) ^ (d & 15)) << 2) + (v & 3)] = val;
        bT[(v << 6) + (((d >> 2) ^ (v & 15)) << 2) + (d & 3)] = val;
    }
    __syncthreads();

    const int wave = threadIdx.x >> 6;
    const int lane = threadIdx.x & 63;
    const int tk  = blockIdx.x * 16 + wave;
    const int row = tk >> 3;
    const int h   = tk & 7;
    const bf16* base = qkv + (size_t)row * 1536 + h * 63;
    float q_own = 0.f, k_own = 0.f, v_own = 0.f;
    if (lane < 63) {
        q_own = (float)base[lane] * 1.4426950408889634f;
        k_own = (float)base[504 + lane];
        v_own = (float)base[1008 + lane];
    }

    const float* myT = bT + (lane << 6);
    const int sw = lane & 15;
    float z0 = 0.f, z1 = 0.f, z2 = 0.f, z3 = 0.f;
    #pragma unroll
    for (int g = 0; g < 16; ++g) {
        f32x4 bb = *(const f32x4*)(myT + ((g ^ sw) << 2));
        z0 += __builtin_amdgcn_exp2f(fmaf(rdlane(q_own, 4*g + 0), k_own, bb[0]));
        z1 += __builtin_amdgcn_exp2f(fmaf(rdlane(q_own, 4*g + 1), k_own, bb[1]));
        z2 += __builtin_amdgcn_exp2f(fmaf(rdlane(q_own, 4*g + 2), k_own, bb[2]));
        z3 += __builtin_amdgcn_exp2f(fmaf(rdlane(q_own, 4*g + 3), k_own, bb[3]));
    }
    float Z = (z0 + z1) + (z2 + z3);
    float w_own = (lane < 63) ? v_own / Z : 0.f;

    const float* myR = bR + (lane << 6);
    float a0 = 0.f, a1 = 0.f, a2 = 0.f, a3 = 0.f;
    #pragma unroll
    for (int g = 0; g < 16; ++g) {
        f32x4 bb = *(const f32x4*)(myR + ((g ^ sw) << 2));
        a0 = fmaf(__builtin_amdgcn_exp2f(fmaf(q_own, rdlane(k_own, 4*g + 0), bb[0])),
                  rdlane(w_own, 4*g + 0), a0);
        a1 = fmaf(__builtin_amdgcn_exp2f(fmaf(q_own, rdlane(k_own, 4*g + 1), bb[1])),
                  rdlane(w_own, 4*g + 1), a1);
        a2 = fmaf(__builtin_amdgcn_exp2f(fmaf(q_own, rdlane(k_own, 4*g + 2), bb[2])),
                  rdlane(w_own, 4*g + 2), a2);
        a3 = fmaf(__builtin_amdgcn_exp2f(fmaf(q_own, rdlane(k_own, 4*g + 3), bb[3])),
                  rdlane(w_own, 4*g + 3), a3);
    }
    float acc = (a0 + a1) + (a2 + a3);

    if (lane < 63)
        outp[(size_t)row * 512 + h*63 + lane] = (bf16)acc;
    if (h == 7 && lane == 63) {
        #pragma unroll
        for (int j = 0; j < 8; ++j)
            outp[(size_t)row * 512 + 504 + j] = (bf16)0.f;
    }
}

extern "C" void kernel_launch(void* const* d_in, const int* in_sizes, int n_in,
                              void* d_out, int out_size, void* d_ws, size_t ws_size,
                              hipStream_t stream)
{
    const float* x       = (const float*)d_in[0];
    const float* ln1_w   = (const float*)d_in[1];
    const float* ln1_b   = (const float*)d_in[2];
    const float* qkv_w   = (const float*)d_in[3];
    const float* qkv_b   = (const float*)d_in[4];
    const float* rel_pos = (const float*)d_in[5];
    const float* proj_w  = (const float*)d_in[6];
    const float* proj_b  = (const float*)d_in[7];
    const float* ln2_w   = (const float*)d_in[8];
    const float* ln2_b   = (const float*)d_in[9];
    const float* fc_w    = (const float*)d_in[10];
    const float* fc_b    = (const float*)d_in[11];
    const float* cproj_w = (const float*)d_in[12];
    const float* cproj_b = (const float*)d_in[13];
    float* out = (float*)d_out;

    // ---- workspace layout (bytes) ----
    char* p = (char*)d_ws;
    bf16*  xr      = (bf16*)p;             p += (size_t)2048*1024*2;   // 4 MB
    bf16*  h_bf    = (bf16*)p;             p += (size_t)2048*1024*2;   // 4 MB
    bf16*  wqkv    = (bf16*)p;             p += (size_t)1536*1024*2;   // 3 MB
    bf16*  wproj   = (bf16*)p;             p += (size_t)1024*512*2;    // 1 MB
    bf16*  wfc     = (bf16*)p;             p += (size_t)4096*1024*2;   // 8 MB
    bf16*  wcproj  = (bf16*)p;             p += (size_t)1024*4096*2;   // 8 MB
    float* qkvb_p  = (float*)p;            p += 8192;                  // 6 KB
    bf16*  attn_bf = (bf16*)p;             p += (size_t)2048*512*2;    // 2 MB
    bf16*  qkvb    = (bf16*)p;                                         // 6 MB
    bf16*  fc_act  = (bf16*)p;             // 16 MB, overlaps qkvb (dead after attn)
    bf16*  proj_part = qkvb;               // 2 x 4 MB (dead before fc writes fc_act)
    // cproj partials: 4 x 4 MB = 16 MB at d_ws start, over xr/h_bf/wqkv/wproj
    // (+4 MB into wfc) — all dead by cproj time (fc completed before cproj).
    bf16*  cp_part = (bf16*)d_ws;

    conv_all_kernel<<<5121, 256, 0, stream>>>(qkv_w, proj_w, fc_w, cproj_w, qkv_b,
                                              wqkv, wproj, wfc, wcproj, qkvb_p);
    rotary_ln_kernel<<<2048, 256, 0, stream>>>(x, ln1_w, ln1_b, xr, h_bf);
    // qkv: M=2048 N=1536 K=1024 -> 12x32 = 384 WGs
    gemm7_kernel<0><<<dim3(12,32,1), 256, 0, stream>>>(h_bf, wqkv, qkvb_p,
                                                       qkvb, 1536, 1024, 1024);
    attn3_kernel<<<1024, 1024, 0, stream>>>(qkvb, rel_pos, attn_bf);
    // proj: M=2048 N=1024 K=512, split-K2 -> 8x32x2 = 512 WGs
    gemm7_kernel<3><<<dim3(8,32,2), 256, 0, stream>>>(attn_bf, wproj, nullptr,
                                                      proj_part, 1024, 512, 256);
    reduceln_kernel<<<2048, 256, 0, stream>>>(proj_part, proj_b, xr,
                                              ln2_w, ln2_b, out, h_bf);
    // fc: M=2048 N=4096 K=1024 -> gemm11 32x16 = 512 WGs, 8 waves (16 w/CU)
    gemm11_kernel<1><<<dim3(32,16,1), 512, 0, stream>>>(h_bf, wfc, fc_b,
                                                        fc_act, 4096, 1024, 1024);
    // cproj: M=2048 N=1024 K=4096, split-K4 -> gemm11 8x16x4 = 512 WGs
    gemm11_kernel<3><<<dim3(8,16,4), 512, 0, stream>>>(fc_act, wcproj, nullptr,
                                                       cp_part, 1024, 4096, 1024);
    reduce_kernel<4><<<2048, 256, 0, stream>>>(cp_part, cproj_b, out, out);
}

// Round 18
// 125.993 us; speedup vs baseline: 1.1786x; 1.0528x over previous
//
#include <hip/hip_runtime.h>
#include <hip/hip_bf16.h>

// Shapes (fixed): B=2 T=1024 E=1024 H=8 W=31 D=63
// NTOK=2048, H*D=504 (pad 512), 3*H*D=1512 (pad 1536), 4E=4096

typedef __bf16 bf16;
typedef bf16 bf16x8 __attribute__((ext_vector_type(8)));
typedef bf16 bf16x4 __attribute__((ext_vector_type(4)));
typedef bf16 bf16x2 __attribute__((ext_vector_type(2)));
typedef float f32x4 __attribute__((ext_vector_type(4)));

__device__ __forceinline__ float rdlane(float x, int l)
{
    return __int_as_float(__builtin_amdgcn_readlane(__float_as_int(x), l));
}

// ---------------- fused rotary + layernorm1 (xr stored bf16) ---------------
__global__ __launch_bounds__(256) void rotary_ln_kernel(
    const float* __restrict__ x, const float* __restrict__ w,
    const float* __restrict__ b, bf16* __restrict__ xr, bf16* __restrict__ Y)
{
    const int row = blockIdx.x;
    const int tid = threadIdx.x;
    float2 xv = *(const float2*)(x + (size_t)row * 512 + tid * 2);
    float i0 = exp2f(-(float)(2*tid)     * 0.025952563241307518f);
    float i1 = exp2f(-(float)(2*tid + 1) * 0.025952563241307518f);
    float a0 = xv.x * i0, a1 = xv.y * i1;
    float s0 = sinf(a0), s1 = sinf(a1);
    float c0 = cosf(a0), c1 = cosf(a1);
    bf16x2 xs, xc;
    xs[0] = (bf16)s0; xs[1] = (bf16)s1;
    xc[0] = (bf16)c0; xc[1] = (bf16)c1;
    *(bf16x2*)(xr + (size_t)row * 1024 + tid*2)       = xs;
    *(bf16x2*)(xr + (size_t)row * 1024 + 512 + tid*2) = xc;
    float s  = s0 + s1 + c0 + c1;
    float ss = s0*s0 + s1*s1 + c0*c0 + c1*c1;
    #pragma unroll
    for (int off = 32; off > 0; off >>= 1) {
        s  += __shfl_down(s, off);
        ss += __shfl_down(ss, off);
    }
    __shared__ float rs[4], rss[4];
    int wave = tid >> 6, lane = tid & 63;
    if (lane == 0) { rs[wave] = s; rss[wave] = ss; }
    __syncthreads();
    s  = rs[0] + rs[1] + rs[2] + rs[3];
    ss = rss[0] + rss[1] + rss[2] + rss[3];
    float mu   = s * (1.f / 1024.f);
    float var  = ss * (1.f / 1024.f) - mu * mu;
    float rstd = rsqrtf(var + 1e-5f);
    float2 w0 = *(const float2*)(w + tid*2);
    float2 b0 = *(const float2*)(b + tid*2);
    float2 w1 = *(const float2*)(w + 512 + tid*2);
    float2 b1 = *(const float2*)(b + 512 + tid*2);
    bf16x2 y0, y1;
    y0[0] = (bf16)((s0 - mu) * rstd * w0.x + b0.x);
    y0[1] = (bf16)((s1 - mu) * rstd * w0.y + b0.y);
    y1[0] = (bf16)((c0 - mu) * rstd * w1.x + b1.x);
    y1[1] = (bf16)((c1 - mu) * rstd * w1.y + b1.y);
    *(bf16x2*)(Y + (size_t)row * 1024 + tid*2)       = y0;
    *(bf16x2*)(Y + (size_t)row * 1024 + 512 + tid*2) = y1;
}

// ---------------- fused weight converts (fp32->bf16, zero-pad) + bias pad --
__device__ __forceinline__ void conv_chunk(
    const float* __restrict__ src, bf16* __restrict__ dst,
    int ci, int N, int K, int Kp)
{
    int kpc = Kp >> 3;
    int r  = ci / kpc;
    int kc = (ci - r * kpc) << 3;
    bf16x8 o;
    if (r < N && kc < K) {
        float4 f0 = *(const float4*)(src + (size_t)r * K + kc);
        float4 f1 = *(const float4*)(src + (size_t)r * K + kc + 4);
        o[0]=(bf16)f0.x; o[1]=(bf16)f0.y; o[2]=(bf16)f0.z; o[3]=(bf16)f0.w;
        o[4]=(bf16)f1.x; o[5]=(bf16)f1.y; o[6]=(bf16)f1.z; o[7]=(bf16)f1.w;
    } else {
        #pragma unroll
        for (int j = 0; j < 8; ++j) o[j] = (bf16)0.f;
    }
    *(bf16x8*)(dst + (size_t)r * Kp + kc) = o;
}

__global__ __launch_bounds__(256) void conv_all_kernel(
    const float* __restrict__ qkv_w, const float* __restrict__ proj_w,
    const float* __restrict__ fc_w,  const float* __restrict__ cproj_w,
    const float* __restrict__ qkv_b,
    bf16* __restrict__ wqkv, bf16* __restrict__ wproj,
    bf16* __restrict__ wfc,  bf16* __restrict__ wcproj,
    float* __restrict__ qkvb_p)
{
    if (blockIdx.x == 5120) {
        for (int i = threadIdx.x; i < 1536; i += 256)
            qkvb_p[i] = (i < 1512) ? qkv_b[i] : 0.f;
        return;
    }
    int idx = blockIdx.x * 256 + threadIdx.x;
    if      (idx < 196608)  conv_chunk(qkv_w,   wqkv,   idx,          1512, 1024, 1024);
    else if (idx < 262144)  conv_chunk(proj_w,  wproj,  idx - 196608, 1024,  504,  512);
    else if (idx < 786432)  conv_chunk(fc_w,    wfc,    idx - 262144, 4096, 1024, 1024);
    else                    conv_chunk(cproj_w, wcproj, idx - 786432, 1024, 4096, 4096);
}

// ---------------- helpers ---------------------------------------------------
template<int N> __device__ __forceinline__ void vmwait()
{
    if constexpr      (N==0) asm volatile("s_waitcnt vmcnt(0)" ::: "memory");
    else if constexpr (N==3) asm volatile("s_waitcnt vmcnt(3)" ::: "memory");
}
__device__ __forceinline__ void lgkmwait0()
{
    asm volatile("s_waitcnt lgkmcnt(0)" ::: "memory");
}
__device__ __forceinline__ void hw_barrier()
{
    asm volatile("s_barrier" ::: "memory");
}
__device__ __forceinline__ void gload16(const char* src, char* ldsdst)
{
    __builtin_amdgcn_global_load_lds(
        (const __attribute__((address_space(1))) void*)src,
        (__attribute__((address_space(3))) void*)ldsdst, 16, 0, 0);
}
__device__ __forceinline__ float gelu_exact(float v)
{
    return 0.5f * v * (1.f + erff(v * 0.70710678118654752f));
}

// ---------------- gemm12: 128x128 tile, 8 waves 2x4, BK=64, 2-buf ----------
// gemm11 geometry (16 waves/CU, the session's proven controlling variable)
// with BK=64: half the iterations (32->16 for fc), half the barrier events,
// double the per-stage load batch (4x16B/thread issued together).
// LDS 2 x 32KB ping-pong = 64 KB -> 2 blk/CU (launch_bounds(512,4)).
// 128B rows -> 8-slot XOR swizzle slot^=(row&7), both sides (rule 21);
// audit: per read group 8 lanes/4-bank-group = 2 lanes/bank = free (m136).
// EPI: 1 gelu->bf16 (+bias), 3 bf16 partial (z-strided)
template<int EPI>
__global__ __launch_bounds__(512, 4) void gemm12_kernel(
    const bf16* __restrict__ A, const bf16* __restrict__ Wt,
    const float* __restrict__ bias, bf16* __restrict__ Cb,
    int N, int Kp, int ksplit)
{
    __shared__ __align__(16) char lds[2][32768];   // per buf: A 16KB | B 16KB

    const int tid  = threadIdx.x;       // 0..511
    const int w    = tid >> 6;
    const int lane = tid & 63;
    const int wm   = w >> 2;            // 0..1 : 64-row band
    const int wn   = w & 3;             // 0..3 : 32-col band
    const int rl   = lane & 15;
    const int slotR = lane >> 4;        // 0..3

    const int gx = gridDim.x, gy = gridDim.y;
    const int nwg = gx * gy * gridDim.z;
    const int chunk = nwg >> 3;
    int id = (blockIdx.z * gy + blockIdx.y) * gx + blockIdx.x;
    int sw = (id & 7) * chunk + (id >> 3);
    const int bx = sw % gx;
    const int t2 = sw / gx;
    const int by = t2 % gy;
    const int bz = t2 / gy;

    const int row0 = by * 128;
    const int col0 = bx * 128;
    const size_t strideBy = (size_t)Kp * 2;
    const size_t kz = (size_t)bz * ksplit * 2;
    const char* Abase = (const char*)A  + (size_t)row0 * strideBy + kz;
    const char* Wbase = (const char*)Wt + (size_t)col0 * strideBy + kz;

    // pre-swizzled global sources (LDS dest linear, rule 21); 2 chunks each
    // of A and B per thread.  Row = 128B = 8 slots of 16B; slot ^= row&7.
    size_t srcO[2];
    #pragma unroll
    for (int i = 0; i < 2; ++i) {
        int ls = i * 512 + tid;             // 0..1023
        int r  = ls >> 3;                   // 0..127
        int s  = (ls & 7) ^ (r & 7);
        srcO[i] = (size_t)r * strideBy + (size_t)(s << 4);
    }

    f32x4 acc[4][2] = {};

    auto STAGE = [&](int buf, int kt) {
        const char* ab = Abase + (size_t)kt * 128;
        const char* wb = Wbase + (size_t)kt * 128;
        #pragma unroll
        for (int i = 0; i < 2; ++i)
            gload16(ab + srcO[i], &lds[buf][0]     + (i * 512 + tid) * 16);
        #pragma unroll
        for (int i = 0; i < 2; ++i)
            gload16(wb + srcO[i], &lds[buf][16384] + (i * 512 + tid) * 16);
    };

    const int niter = ksplit >> 6;      // BK = 64; all call sites = 16
    STAGE(0, 0);
    __syncthreads();
    for (int kt = 0; kt < niter; ++kt) {
        if (kt + 1 < niter)
            STAGE((kt + 1) & 1, kt + 1);    // in flight during compute
        const char* base = lds[kt & 1];
        bf16x8 af[4][2], bfr[2][2];
        #pragma unroll
        for (int mi = 0; mi < 4; ++mi) {
            int rr = wm * 64 + mi * 16 + rl;
            #pragma unroll
            for (int ks = 0; ks < 2; ++ks)
                af[mi][ks] = *(const bf16x8*)
                    (base + (rr << 7) + ((((ks << 2) + slotR) ^ (rr & 7)) << 4));
        }
        #pragma unroll
        for (int nj = 0; nj < 2; ++nj) {
            int rr = wn * 32 + nj * 16 + rl;
            #pragma unroll
            for (int ks = 0; ks < 2; ++ks)
                bfr[nj][ks] = *(const bf16x8*)
                    (base + 16384 + (rr << 7) + ((((ks << 2) + slotR) ^ (rr & 7)) << 4));
        }
        __builtin_amdgcn_s_setprio(1);
        #pragma unroll
        for (int ks = 0; ks < 2; ++ks)
            #pragma unroll
            for (int mi = 0; mi < 4; ++mi)
                #pragma unroll
                for (int nj = 0; nj < 2; ++nj)
                    acc[mi][nj] = __builtin_amdgcn_mfma_f32_16x16x32_bf16(
                        af[mi][ks], bfr[nj][ks], acc[mi][nj], 0, 0, 0);
        __builtin_amdgcn_s_setprio(0);
        __syncthreads();                    // drain loads + protect ping-pong
    }

    // C/D layout: col = lane&15, row = (lane>>4)*4 + reg   [m89/m91]
    const int rq = (lane >> 4) * 4;
    bf16* Cbz = Cb;
    if (EPI == 3) Cbz += (size_t)bz * 2048 * N;
    #pragma unroll
    for (int mi = 0; mi < 4; ++mi) {
        #pragma unroll
        for (int rj = 0; rj < 4; ++rj) {
            int row = row0 + wm * 64 + mi * 16 + rq + rj;
            #pragma unroll
            for (int nj = 0; nj < 2; ++nj) {
                int col = col0 + wn * 32 + nj * 16 + rl;
                float c = acc[mi][nj][rj];
                size_t off = (size_t)row * N + col;
                if (EPI == 1) Cbz[off] = (bf16)gelu_exact(c + bias[col]);
                else          Cbz[off] = (bf16)c;
            }
        }
    }
}

// ---------------- gemm7: 64x128 tile, 4 waves, 3-buf (qkv / proj, R13) -----
template<int EPI>
__global__ __launch_bounds__(256, 4) void gemm7_kernel(
    const bf16* __restrict__ A, const bf16* __restrict__ Wt,
    const float* __restrict__ bias, bf16* __restrict__ Cb,
    int N, int Kp, int ksplit)
{
    __shared__ __align__(16) char lds[3][12288];   // per buf: A 4KB | B 8KB

    const int tid  = threadIdx.x;
    const int w    = tid >> 6;
    const int lane = tid & 63;

    const int gx = gridDim.x, gy = gridDim.y;
    const int nwg = gx * gy * gridDim.z;
    const int chunk = nwg >> 3;
    int id = (blockIdx.z * gy + blockIdx.y) * gx + blockIdx.x;
    int sw = (id & 7) * chunk + (id >> 3);
    const int bx = sw % gx;
    const int t2 = sw / gx;
    const int by = t2 % gy;
    const int bz = t2 / gy;

    const int row0 = by * 64;
    const int col0 = bx * 128;
    const int wr = (w >> 1) * 32;
    const int wc = (w & 1) * 64;
    const int rl = lane & 15;
    const int slotR = lane >> 4;

    const size_t strideBy = (size_t)Kp * 2;
    const size_t kz = (size_t)bz * ksplit * 2;
    const char* Abase = (const char*)A  + (size_t)row0 * strideBy + kz;
    const char* Wbase = (const char*)Wt + (size_t)col0 * strideBy + kz;

    const int arow = tid >> 2;
    const size_t srcA0 = (size_t)arow * strideBy
                       + (size_t)(((tid & 3) ^ ((arow >> 1) & 3)) << 4);
    size_t srcB[2];
    #pragma unroll
    for (int i = 0; i < 2; ++i) {
        int o = (i * 256 + tid) * 16;
        int rr = o >> 6;
        int ss = ((o & 63) >> 4) ^ ((rr >> 1) & 3);
        srcB[i] = (size_t)rr * strideBy + (size_t)(ss << 4);
    }

    f32x4 acc[2][4] = {};

    auto STAGE = [&](int buf, int kt) {
        const char* ab = Abase + (size_t)kt * 64;
        const char* wb = Wbase + (size_t)kt * 64;
        gload16(ab + srcA0, &lds[buf][0] + tid * 16);
        #pragma unroll
        for (int i = 0; i < 2; ++i)
            gload16(wb + srcB[i], &lds[buf][4096] + (i * 256 + tid) * 16);
    };

    const int niter = ksplit >> 5;      // BK = 32
    STAGE(0, 0);
    STAGE(1, 1);
    vmwait<3>();
    hw_barrier();

    int cur = 0, stg = 2;
    for (int kt = 0; kt < niter; ++kt) {
        if (kt + 2 < niter) STAGE(stg, kt + 2);
        const char* base = lds[cur];
        bf16x8 af[2], bfr[4];
        #pragma unroll
        for (int mi = 0; mi < 2; ++mi) {
            int rr = wr + mi * 16 + rl;
            af[mi] = *(const bf16x8*)
                (base + (rr << 6) + ((slotR ^ ((rr >> 1) & 3)) << 4));
        }
        #pragma unroll
        for (int nj = 0; nj < 4; ++nj) {
            int rr = wc + nj * 16 + rl;
            bfr[nj] = *(const bf16x8*)
                (base + 4096 + (rr << 6) + ((slotR ^ ((rr >> 1) & 3)) << 4));
        }
        __builtin_amdgcn_s_setprio(1);
        #pragma unroll
        for (int mi = 0; mi < 2; ++mi)
            #pragma unroll
            for (int nj = 0; nj < 4; ++nj)
                acc[mi][nj] = __builtin_amdgcn_mfma_f32_16x16x32_bf16(
                    af[mi], bfr[nj], acc[mi][nj], 0, 0, 0);
        __builtin_amdgcn_s_setprio(0);

        if (kt + 1 < niter) {
            lgkmwait0();
            if (kt + 2 < niter) vmwait<3>();
            else                vmwait<0>();
            hw_barrier();
        }
        cur = (cur == 2) ? 0 : cur + 1;
        stg = (stg == 2) ? 0 : stg + 1;
    }

    const int rq = (lane >> 4) * 4;
    bf16* Cbz = Cb;
    if (EPI == 3) Cbz += (size_t)bz * 2048 * N;
    #pragma unroll
    for (int mi = 0; mi < 2; ++mi) {
        #pragma unroll
        for (int rj = 0; rj < 4; ++rj) {
            int row = row0 + wr + mi*16 + rq + rj;
            #pragma unroll
            for (int nj = 0; nj < 4; ++nj) {
                int col = col0 + wc + nj*16 + rl;
                float c = acc[mi][nj][rj];
                size_t off = (size_t)row * N + col;
                if (EPI == 0)      Cbz[off] = (bf16)(c + bias[col]);
                else if (EPI == 1) Cbz[off] = (bf16)gelu_exact(c + bias[col]);
                else               Cbz[off] = (bf16)c;
            }
        }
    }
}

// ---------------- split-K reducer: out = R + bias + sum(parts) -------------
template<int P>
__global__ __launch_bounds__(256) void reduce_kernel(
    const bf16* __restrict__ parts, const float* __restrict__ bias,
    const float* R, float* out)
{
    int row = blockIdx.x;
    int c = threadIdx.x * 4;
    size_t off = (size_t)row * 1024 + c;
    float4 bv = *(const float4*)(bias + c);
    float4 o = *(const float4*)(R + off);
    o.x += bv.x; o.y += bv.y; o.z += bv.z; o.w += bv.w;
    #pragma unroll
    for (int p = 0; p < P; ++p) {
        bf16x4 v = *(const bf16x4*)(parts + (size_t)p * 2048 * 1024 + off);
        o.x += (float)v[0]; o.y += (float)v[1];
        o.z += (float)v[2]; o.w += (float)v[3];
    }
    *(float4*)(out + off) = o;
}

// ---------------- fused proj-reduce + LN2 (R is bf16 xr) -------------------
__global__ __launch_bounds__(256) void reduceln_kernel(
    const bf16* __restrict__ parts, const float* __restrict__ bias,
    const bf16* __restrict__ R, const float* __restrict__ lnw,
    const float* __restrict__ lnb, float* __restrict__ out,
    bf16* __restrict__ Y)
{
    int row = blockIdx.x;
    int c = threadIdx.x * 4;
    size_t off = (size_t)row * 1024 + c;
    float4 bv = *(const float4*)(bias + c);
    bf16x4 rv = *(const bf16x4*)(R + off);
    float4 o;
    o.x = (float)rv[0] + bv.x;
    o.y = (float)rv[1] + bv.y;
    o.z = (float)rv[2] + bv.z;
    o.w = (float)rv[3] + bv.w;
    #pragma unroll
    for (int p = 0; p < 2; ++p) {
        bf16x4 v = *(const bf16x4*)(parts + (size_t)p * 2048 * 1024 + off);
        o.x += (float)v[0]; o.y += (float)v[1];
        o.z += (float)v[2]; o.w += (float)v[3];
    }
    *(float4*)(out + off) = o;
    float s  = o.x + o.y + o.z + o.w;
    float ss = o.x*o.x + o.y*o.y + o.z*o.z + o.w*o.w;
    #pragma unroll
    for (int of = 32; of > 0; of >>= 1) {
        s  += __shfl_down(s, of);
        ss += __shfl_down(ss, of);
    }
    __shared__ float rs[4], rss[4];
    int wave = threadIdx.x >> 6, lane = threadIdx.x & 63;
    if (lane == 0) { rs[wave] = s; rss[wave] = ss; }
    __syncthreads();
    s  = rs[0] + rs[1] + rs[2] + rs[3];
    ss = rss[0] + rss[1] + rss[2] + rss[3];
    float mu  = s * (1.f / 1024.f);
    float var = ss * (1.f / 1024.f) - mu * mu;
    float rstd = rsqrtf(var + 1e-5f);
    float4 wv = *(const float4*)(lnw + c);
    float4 lb = *(const float4*)(lnb + c);
    bf16 y[4];
    y[0] = (bf16)((o.x - mu) * rstd * wv.x + lb.x);
    y[1] = (bf16)((o.y - mu) * rstd * wv.y + lb.y);
    y[2] = (bf16)((o.z - mu) * rstd * wv.z + lb.z);
    y[3] = (bf16)((o.w - mu) * rstd * wv.w + lb.w);
    *(uint2*)(Y + (size_t)row * 1024 + c) = *(uint2*)y;
}

// ---------------- windowed attention v3: 16 waves/block, exp2 tables -------
__global__ __launch_bounds__(1024) void attn3_kernel(
    const bf16* __restrict__ qkv, const float* __restrict__ rel_pos,
    bf16* __restrict__ outp)
{
    __shared__ float bR[4096];   // row-major bias*log2e, swizzled 16B slots
    __shared__ float bT[4096];   // transposed
    for (int i = threadIdx.x; i < 4096; i += 1024) {
        int d = i >> 6, v = i & 63;
        float val = (d < 63 && v < 63)
                  ? rel_pos[((d + 32) % 63) * 63 + v] * 1.4426950408889634f
                  : -1e30f;
        bR[(d << 6) + (((v >> 2) ^ (d & 15)) << 2) + (v & 3)] = val;
        bT[(v << 6) + (((d >> 2) ^ (v & 15)) << 2) + (d & 3)] = val;
    }
    __syncthreads();

    const int wave = threadIdx.x >> 6;
    const int lane = threadIdx.x & 63;
    const int tk  = blockIdx.x * 16 + wave;
    const int row = tk >> 3;
    const int h   = tk & 7;
    const bf16* base = qkv + (size_t)row * 1536 + h * 63;
    float q_own = 0.f, k_own = 0.f, v_own = 0.f;
    if (lane < 63) {
        q_own = (float)base[lane] * 1.4426950408889634f;
        k_own = (float)base[504 + lane];
        v_own = (float)base[1008 + lane];
    }

    const float* myT = bT + (lane << 6);
    const int sw = lane & 15;
    float z0 = 0.f, z1 = 0.f, z2 = 0.f, z3 = 0.f;
    #pragma unroll
    for (int g = 0; g < 16; ++g) {
        f32x4 bb = *(const f32x4*)(myT + ((g ^ sw) << 2));
        z0 += __builtin_amdgcn_exp2f(fmaf(rdlane(q_own, 4*g + 0), k_own, bb[0]));
        z1 += __builtin_amdgcn_exp2f(fmaf(rdlane(q_own, 4*g + 1), k_own, bb[1]));
        z2 += __builtin_amdgcn_exp2f(fmaf(rdlane(q_own, 4*g + 2), k_own, bb[2]));
        z3 += __builtin_amdgcn_exp2f(fmaf(rdlane(q_own, 4*g + 3), k_own, bb[3]));
    }
    float Z = (z0 + z1) + (z2 + z3);
    float w_own = (lane < 63) ? v_own / Z : 0.f;

    const float* myR = bR + (lane << 6);
    float a0 = 0.f, a1 = 0.f, a2 = 0.f, a3 = 0.f;
    #pragma unroll
    for (int g = 0; g < 16; ++g) {
        f32x4 bb = *(const f32x4*)(myR + ((g ^ sw) << 2));
        a0 = fmaf(__builtin_amdgcn_exp2f(fmaf(q_own, rdlane(k_own, 4*g + 0), bb[0])),
                  rdlane(w_own, 4*g + 0), a0);
        a1 = fmaf(__builtin_amdgcn_exp2f(fmaf(q_own, rdlane(k_own, 4*g + 1), bb[1])),
                  rdlane(w_own, 4*g + 1), a1);
        a2 = fmaf(__builtin_amdgcn_exp2f(fmaf(q_own, rdlane(k_own, 4*g + 2), bb[2])),
                  rdlane(w_own, 4*g + 2), a2);
        a3 = fmaf(__builtin_amdgcn_exp2f(fmaf(q_own, rdlane(k_own, 4*g + 3), bb[3])),
                  rdlane(w_own, 4*g + 3), a3);
    }
    float acc = (a0 + a1) + (a2 + a3);

    if (lane < 63)
        outp[(size_t)row * 512 + h*63 + lane] = (bf16)acc;
    if (h == 7 && lane == 63) {
        #pragma unroll
        for (int j = 0; j < 8; ++j)
            outp[(size_t)row * 512 + 504 + j] = (bf16)0.f;
    }
}

extern "C" void kernel_launch(void* const* d_in, const int* in_sizes, int n_in,
                              void* d_out, int out_size, void* d_ws, size_t ws_size,
                              hipStream_t stream)
{
    const float* x       = (const float*)d_in[0];
    const float* ln1_w   = (const float*)d_in[1];
    const float* ln1_b   = (const float*)d_in[2];
    const float* qkv_w   = (const float*)d_in[3];
    const float* qkv_b   = (const float*)d_in[4];
    const float* rel_pos = (const float*)d_in[5];
    const float* proj_w  = (const float*)d_in[6];
    const float* proj_b  = (const float*)d_in[7];
    const float* ln2_w   = (const float*)d_in[8];
    const float* ln2_b   = (const float*)d_in[9];
    const float* fc_w    = (const float*)d_in[10];
    const float* fc_b    = (const float*)d_in[11];
    const float* cproj_w = (const float*)d_in[12];
    const float* cproj_b = (const float*)d_in[13];
    float* out = (float*)d_out;

    // ---- workspace layout (bytes) ----
    char* p = (char*)d_ws;
    bf16*  xr      = (bf16*)p;             p += (size_t)2048*1024*2;   // 4 MB
    bf16*  h_bf    = (bf16*)p;             p += (size_t)2048*1024*2;   // 4 MB
    bf16*  wqkv    = (bf16*)p;             p += (size_t)1536*1024*2;   // 3 MB
    bf16*  wproj   = (bf16*)p;             p += (size_t)1024*512*2;    // 1 MB
    bf16*  wfc     = (bf16*)p;             p += (size_t)4096*1024*2;   // 8 MB
    bf16*  wcproj  = (bf16*)p;             p += (size_t)1024*4096*2;   // 8 MB
    float* qkvb_p  = (float*)p;            p += 8192;                  // 6 KB
    bf16*  attn_bf = (bf16*)p;             p += (size_t)2048*512*2;    // 2 MB
    bf16*  qkvb    = (bf16*)p;                                         // 6 MB
    bf16*  fc_act  = (bf16*)p;             // 16 MB, overlaps qkvb (dead after attn)
    bf16*  proj_part = qkvb;               // 2 x 4 MB (dead before fc writes fc_act)
    // cproj partials: 4 x 4 MB = 16 MB at d_ws start, over xr/h_bf/wqkv/wproj
    // (+4 MB into wfc) — all dead by cproj time.
    bf16*  cp_part = (bf16*)d_ws;

    conv_all_kernel<<<5121, 256, 0, stream>>>(qkv_w, proj_w, fc_w, cproj_w, qkv_b,
                                              wqkv, wproj, wfc, wcproj, qkvb_p);
    rotary_ln_kernel<<<2048, 256, 0, stream>>>(x, ln1_w, ln1_b, xr, h_bf);
    // qkv: M=2048 N=1536 K=1024 -> 12x32 = 384 WGs
    gemm7_kernel<0><<<dim3(12,32,1), 256, 0, stream>>>(h_bf, wqkv, qkvb_p,
                                                       qkvb, 1536, 1024, 1024);
    attn3_kernel<<<1024, 1024, 0, stream>>>(qkvb, rel_pos, attn_bf);
    // proj: M=2048 N=1024 K=512, split-K2 -> 8x32x2 = 512 WGs
    gemm7_kernel<3><<<dim3(8,32,2), 256, 0, stream>>>(attn_bf, wproj, nullptr,
                                                      proj_part, 1024, 512, 256);
    reduceln_kernel<<<2048, 256, 0, stream>>>(proj_part, proj_b, xr,
                                              ln2_w, ln2_b, out, h_bf);
    // fc: M=2048 N=4096 K=1024 -> gemm12 32x16 = 512 WGs, 8 waves (16 w/CU)
    gemm12_kernel<1><<<dim3(32,16,1), 512, 0, stream>>>(h_bf, wfc, fc_b,
                                                        fc_act, 4096, 1024, 1024);
    // cproj: M=2048 N=1024 K=4096, split-K4 -> gemm12 8x16x4 = 512 WGs
    gemm12_kernel<3><<<dim3(8,16,4), 512, 0, stream>>>(fc_act, wcproj, nullptr,
                                                       cp_part, 1024, 4096, 1024);
    reduce_kernel<4><<<2048, 256, 0, stream>>>(cp_part, cproj_b, out, out);
}

// Round 19
// 124.522 us; speedup vs baseline: 1.1925x; 1.0118x over previous
//
#include <hip/hip_runtime.h>
#include <hip/hip_bf16.h>

// Shapes (fixed): B=2 T=1024 E=1024 H=8 W=31 D=63
// NTOK=2048, H*D=504 (pad 512), 3*H*D=1512 (pad 1536), 4E=4096

typedef __bf16 bf16;
typedef bf16 bf16x8 __attribute__((ext_vector_type(8)));
typedef bf16 bf16x4 __attribute__((ext_vector_type(4)));
typedef bf16 bf16x2 __attribute__((ext_vector_type(2)));
typedef float f32x4 __attribute__((ext_vector_type(4)));

__device__ __forceinline__ float rdlane(float x, int l)
{
    return __int_as_float(__builtin_amdgcn_readlane(__float_as_int(x), l));
}

// ---------------- fused rotary + layernorm1 (xr stored bf16) ---------------
__global__ __launch_bounds__(256) void rotary_ln_kernel(
    const float* __restrict__ x, const float* __restrict__ w,
    const float* __restrict__ b, bf16* __restrict__ xr, bf16* __restrict__ Y)
{
    const int row = blockIdx.x;
    const int tid = threadIdx.x;
    float2 xv = *(const float2*)(x + (size_t)row * 512 + tid * 2);
    float i0 = exp2f(-(float)(2*tid)     * 0.025952563241307518f);
    float i1 = exp2f(-(float)(2*tid + 1) * 0.025952563241307518f);
    float a0 = xv.x * i0, a1 = xv.y * i1;
    float s0 = sinf(a0), s1 = sinf(a1);
    float c0 = cosf(a0), c1 = cosf(a1);
    bf16x2 xs, xc;
    xs[0] = (bf16)s0; xs[1] = (bf16)s1;
    xc[0] = (bf16)c0; xc[1] = (bf16)c1;
    *(bf16x2*)(xr + (size_t)row * 1024 + tid*2)       = xs;
    *(bf16x2*)(xr + (size_t)row * 1024 + 512 + tid*2) = xc;
    float s  = s0 + s1 + c0 + c1;
    float ss = s0*s0 + s1*s1 + c0*c0 + c1*c1;
    #pragma unroll
    for (int off = 32; off > 0; off >>= 1) {
        s  += __shfl_down(s, off);
        ss += __shfl_down(ss, off);
    }
    __shared__ float rs[4], rss[4];
    int wave = tid >> 6, lane = tid & 63;
    if (lane == 0) { rs[wave] = s; rss[wave] = ss; }
    __syncthreads();
    s  = rs[0] + rs[1] + rs[2] + rs[3];
    ss = rss[0] + rss[1] + rss[2] + rss[3];
    float mu   = s * (1.f / 1024.f);
    float var  = ss * (1.f / 1024.f) - mu * mu;
    float rstd = rsqrtf(var + 1e-5f);
    float2 w0 = *(const float2*)(w + tid*2);
    float2 b0 = *(const float2*)(b + tid*2);
    float2 w1 = *(const float2*)(w + 512 + tid*2);
    float2 b1 = *(const float2*)(b + 512 + tid*2);
    bf16x2 y0, y1;
    y0[0] = (bf16)((s0 - mu) * rstd * w0.x + b0.x);
    y0[1] = (bf16)((s1 - mu) * rstd * w0.y + b0.y);
    y1[0] = (bf16)((c0 - mu) * rstd * w1.x + b1.x);
    y1[1] = (bf16)((c1 - mu) * rstd * w1.y + b1.y);
    *(bf16x2*)(Y + (size_t)row * 1024 + tid*2)       = y0;
    *(bf16x2*)(Y + (size_t)row * 1024 + 512 + tid*2) = y1;
}

// ---------------- fused weight converts (fp32->bf16, zero-pad) + bias pad --
__device__ __forceinline__ void conv_chunk(
    const float* __restrict__ src, bf16* __restrict__ dst,
    int ci, int N, int K, int Kp)
{
    int kpc = Kp >> 3;
    int r  = ci / kpc;
    int kc = (ci - r * kpc) << 3;
    bf16x8 o;
    if (r < N && kc < K) {
        float4 f0 = *(const float4*)(src + (size_t)r * K + kc);
        float4 f1 = *(const float4*)(src + (size_t)r * K + kc + 4);
        o[0]=(bf16)f0.x; o[1]=(bf16)f0.y; o[2]=(bf16)f0.z; o[3]=(bf16)f0.w;
        o[4]=(bf16)f1.x; o[5]=(bf16)f1.y; o[6]=(bf16)f1.z; o[7]=(bf16)f1.w;
    } else {
        #pragma unroll
        for (int j = 0; j < 8; ++j) o[j] = (bf16)0.f;
    }
    *(bf16x8*)(dst + (size_t)r * Kp + kc) = o;
}

__global__ __launch_bounds__(256) void conv_all_kernel(
    const float* __restrict__ qkv_w, const float* __restrict__ proj_w,
    const float* __restrict__ fc_w,  const float* __restrict__ cproj_w,
    const float* __restrict__ qkv_b,
    bf16* __restrict__ wqkv, bf16* __restrict__ wproj,
    bf16* __restrict__ wfc,  bf16* __restrict__ wcproj,
    float* __restrict__ qkvb_p)
{
    if (blockIdx.x == 5120) {
        for (int i = threadIdx.x; i < 1536; i += 256)
            qkvb_p[i] = (i < 1512) ? qkv_b[i] : 0.f;
        return;
    }
    int idx = blockIdx.x * 256 + threadIdx.x;
    if      (idx < 196608)  conv_chunk(qkv_w,   wqkv,   idx,          1512, 1024, 1024);
    else if (idx < 262144)  conv_chunk(proj_w,  wproj,  idx - 196608, 1024,  504,  512);
    else if (idx < 786432)  conv_chunk(fc_w,    wfc,    idx - 262144, 4096, 1024, 1024);
    else                    conv_chunk(cproj_w, wcproj, idx - 786432, 1024, 4096, 4096);
}

// ---------------- helpers ---------------------------------------------------
__device__ __forceinline__ void gload16(const char* src, char* ldsdst)
{
    __builtin_amdgcn_global_load_lds(
        (const __attribute__((address_space(1))) void*)src,
        (__attribute__((address_space(3))) void*)ldsdst, 16, 0, 0);
}
__device__ __forceinline__ float gelu_exact(float v)
{
    return 0.5f * v * (1.f + erff(v * 0.70710678118654752f));
}

// ---------------- gemm12: 128x128 tile, 8 waves 2x4, BK=64, 2-buf ----------
// R18 best for fc/cproj: 512 WGs -> 2 blk/CU x 8 waves = 16 waves/CU.
// BK=64 halves iterations/barriers; 4x16B loads/thread/stage batched.
// 128B rows -> 8-slot XOR swizzle slot^=(row&7), both sides (rule 21).
// EPI: 1 gelu->bf16 (+bias), 3 bf16 partial (z-strided)
template<int EPI>
__global__ __launch_bounds__(512, 4) void gemm12_kernel(
    const bf16* __restrict__ A, const bf16* __restrict__ Wt,
    const float* __restrict__ bias, bf16* __restrict__ Cb,
    int N, int Kp, int ksplit)
{
    __shared__ __align__(16) char lds[2][32768];   // per buf: A 16KB | B 16KB

    const int tid  = threadIdx.x;       // 0..511
    const int w    = tid >> 6;
    const int lane = tid & 63;
    const int wm   = w >> 2;            // 0..1 : 64-row band
    const int wn   = w & 3;             // 0..3 : 32-col band
    const int rl   = lane & 15;
    const int slotR = lane >> 4;        // 0..3

    const int gx = gridDim.x, gy = gridDim.y;
    const int nwg = gx * gy * gridDim.z;
    const int chunk = nwg >> 3;
    int id = (blockIdx.z * gy + blockIdx.y) * gx + blockIdx.x;
    int sw = (id & 7) * chunk + (id >> 3);
    const int bx = sw % gx;
    const int t2 = sw / gx;
    const int by = t2 % gy;
    const int bz = t2 / gy;

    const int row0 = by * 128;
    const int col0 = bx * 128;
    const size_t strideBy = (size_t)Kp * 2;
    const size_t kz = (size_t)bz * ksplit * 2;
    const char* Abase = (const char*)A  + (size_t)row0 * strideBy + kz;
    const char* Wbase = (const char*)Wt + (size_t)col0 * strideBy + kz;

    size_t srcO[2];
    #pragma unroll
    for (int i = 0; i < 2; ++i) {
        int ls = i * 512 + tid;             // 0..1023
        int r  = ls >> 3;                   // 0..127
        int s  = (ls & 7) ^ (r & 7);
        srcO[i] = (size_t)r * strideBy + (size_t)(s << 4);
    }

    f32x4 acc[4][2] = {};

    auto STAGE = [&](int buf, int kt) {
        const char* ab = Abase + (size_t)kt * 128;
        const char* wb = Wbase + (size_t)kt * 128;
        #pragma unroll
        for (int i = 0; i < 2; ++i)
            gload16(ab + srcO[i], &lds[buf][0]     + (i * 512 + tid) * 16);
        #pragma unroll
        for (int i = 0; i < 2; ++i)
            gload16(wb + srcO[i], &lds[buf][16384] + (i * 512 + tid) * 16);
    };

    const int niter = ksplit >> 6;      // BK = 64
    STAGE(0, 0);
    __syncthreads();
    for (int kt = 0; kt < niter; ++kt) {
        if (kt + 1 < niter)
            STAGE((kt + 1) & 1, kt + 1);
        const char* base = lds[kt & 1];
        bf16x8 af[4][2], bfr[2][2];
        #pragma unroll
        for (int mi = 0; mi < 4; ++mi) {
            int rr = wm * 64 + mi * 16 + rl;
            #pragma unroll
            for (int ks = 0; ks < 2; ++ks)
                af[mi][ks] = *(const bf16x8*)
                    (base + (rr << 7) + ((((ks << 2) + slotR) ^ (rr & 7)) << 4));
        }
        #pragma unroll
        for (int nj = 0; nj < 2; ++nj) {
            int rr = wn * 32 + nj * 16 + rl;
            #pragma unroll
            for (int ks = 0; ks < 2; ++ks)
                bfr[nj][ks] = *(const bf16x8*)
                    (base + 16384 + (rr << 7) + ((((ks << 2) + slotR) ^ (rr & 7)) << 4));
        }
        __builtin_amdgcn_s_setprio(1);
        #pragma unroll
        for (int ks = 0; ks < 2; ++ks)
            #pragma unroll
            for (int mi = 0; mi < 4; ++mi)
                #pragma unroll
                for (int nj = 0; nj < 2; ++nj)
                    acc[mi][nj] = __builtin_amdgcn_mfma_f32_16x16x32_bf16(
                        af[mi][ks], bfr[nj][ks], acc[mi][nj], 0, 0, 0);
        __builtin_amdgcn_s_setprio(0);
        __syncthreads();
    }

    // C/D layout: col = lane&15, row = (lane>>4)*4 + reg   [m89/m91]
    const int rq = (lane >> 4) * 4;
    bf16* Cbz = Cb;
    if (EPI == 3) Cbz += (size_t)bz * 2048 * N;
    #pragma unroll
    for (int mi = 0; mi < 4; ++mi) {
        #pragma unroll
        for (int rj = 0; rj < 4; ++rj) {
            int row = row0 + wm * 64 + mi * 16 + rq + rj;
            #pragma unroll
            for (int nj = 0; nj < 2; ++nj) {
                int col = col0 + wn * 32 + nj * 16 + rl;
                float c = acc[mi][nj][rj];
                size_t off = (size_t)row * N + col;
                if (EPI == 1) Cbz[off] = (bf16)gelu_exact(c + bias[col]);
                else          Cbz[off] = (bf16)c;
            }
        }
    }
}

// ---------------- gemm12s: 64x128 tile, 8 waves 2x4, BK=64, 2-buf ----------
// Same template as gemm12, scaled to BM=64 for qkv/proj: per-wave 32x32
// (acc[2][2]).  LDS 2 x (A 8KB + B 16KB) = 48 KB -> 2 blk/CU cap; qkv grid
// 384 WGs -> 12 waves/CU (vs gemm7's 6), proj 512 WGs -> 16 waves/CU.
// EPI: 0 bf16 out (+bias), 3 bf16 partial (z-strided)
template<int EPI>
__global__ __launch_bounds__(512, 4) void gemm12s_kernel(
    const bf16* __restrict__ A, const bf16* __restrict__ Wt,
    const float* __restrict__ bias, bf16* __restrict__ Cb,
    int N, int Kp, int ksplit)
{
    __shared__ __align__(16) char lds[2][24576];   // per buf: A 8KB | B 16KB

    const int tid  = threadIdx.x;       // 0..511
    const int w    = tid >> 6;
    const int lane = tid & 63;
    const int wm   = w >> 2;            // 0..1 : 32-row band
    const int wn   = w & 3;             // 0..3 : 32-col band
    const int rl   = lane & 15;
    const int slotR = lane >> 4;        // 0..3

    const int gx = gridDim.x, gy = gridDim.y;
    const int nwg = gx * gy * gridDim.z;
    const int chunk = nwg >> 3;
    int id = (blockIdx.z * gy + blockIdx.y) * gx + blockIdx.x;
    int sw = (id & 7) * chunk + (id >> 3);
    const int bx = sw % gx;
    const int t2 = sw / gx;
    const int by = t2 % gy;
    const int bz = t2 / gy;

    const int row0 = by * 64;
    const int col0 = bx * 128;
    const size_t strideBy = (size_t)Kp * 2;
    const size_t kz = (size_t)bz * ksplit * 2;
    const char* Abase = (const char*)A  + (size_t)row0 * strideBy + kz;
    const char* Wbase = (const char*)Wt + (size_t)col0 * strideBy + kz;

    // A: 512 chunks (64 rows x 8 slots) -> 1 chunk/thread.
    // B: 1024 chunks (128 rows x 8 slots) -> 2 chunks/thread.
    const int ra = tid >> 3;
    const size_t srcA0 = (size_t)ra * strideBy
                       + (size_t)(((tid & 7) ^ (ra & 7)) << 4);
    size_t srcB[2];
    #pragma unroll
    for (int i = 0; i < 2; ++i) {
        int ls = i * 512 + tid;
        int r  = ls >> 3;
        int s  = (ls & 7) ^ (r & 7);
        srcB[i] = (size_t)r * strideBy + (size_t)(s << 4);
    }

    f32x4 acc[2][2] = {};

    auto STAGE = [&](int buf, int kt) {
        const char* ab = Abase + (size_t)kt * 128;
        const char* wb = Wbase + (size_t)kt * 128;
        gload16(ab + srcA0, &lds[buf][0] + tid * 16);
        #pragma unroll
        for (int i = 0; i < 2; ++i)
            gload16(wb + srcB[i], &lds[buf][8192] + (i * 512 + tid) * 16);
    };

    const int niter = ksplit >> 6;      // BK = 64; qkv 16, proj 4
    STAGE(0, 0);
    __syncthreads();
    for (int kt = 0; kt < niter; ++kt) {
        if (kt + 1 < niter)
            STAGE((kt + 1) & 1, kt + 1);
        const char* base = lds[kt & 1];
        bf16x8 af[2][2], bfr[2][2];
        #pragma unroll
        for (int mi = 0; mi < 2; ++mi) {
            int rr = wm * 32 + mi * 16 + rl;
            #pragma unroll
            for (int ks = 0; ks < 2; ++ks)
                af[mi][ks] = *(const bf16x8*)
                    (base + (rr << 7) + ((((ks << 2) + slotR) ^ (rr & 7)) << 4));
        }
        #pragma unroll
        for (int nj = 0; nj < 2; ++nj) {
            int rr = wn * 32 + nj * 16 + rl;
            #pragma unroll
            for (int ks = 0; ks < 2; ++ks)
                bfr[nj][ks] = *(const bf16x8*)
                    (base + 8192 + (rr << 7) + ((((ks << 2) + slotR) ^ (rr & 7)) << 4));
        }
        __builtin_amdgcn_s_setprio(1);
        #pragma unroll
        for (int ks = 0; ks < 2; ++ks)
            #pragma unroll
            for (int mi = 0; mi < 2; ++mi)
                #pragma unroll
                for (int nj = 0; nj < 2; ++nj)
                    acc[mi][nj] = __builtin_amdgcn_mfma_f32_16x16x32_bf16(
                        af[mi][ks], bfr[nj][ks], acc[mi][nj], 0, 0, 0);
        __builtin_amdgcn_s_setprio(0);
        __syncthreads();
    }

    // C/D layout: col = lane&15, row = (lane>>4)*4 + reg   [m89/m91]
    const int rq = (lane >> 4) * 4;
    bf16* Cbz = Cb;
    if (EPI == 3) Cbz += (size_t)bz * 2048 * N;
    #pragma unroll
    for (int mi = 0; mi < 2; ++mi) {
        #pragma unroll
        for (int rj = 0; rj < 4; ++rj) {
            int row = row0 + wm * 32 + mi * 16 + rq + rj;
            #pragma unroll
            for (int nj = 0; nj < 2; ++nj) {
                int col = col0 + wn * 32 + nj * 16 + rl;
                float c = acc[mi][nj][rj];
                size_t off = (size_t)row * N + col;
                if (EPI == 0) Cbz[off] = (bf16)(c + bias[col]);
                else          Cbz[off] = (bf16)c;
            }
        }
    }
}

// ---------------- split-K reducer: out = R + bias + sum(parts) -------------
template<int P>
__global__ __launch_bounds__(256) void reduce_kernel(
    const bf16* __restrict__ parts, const float* __restrict__ bias,
    const float* R, float* out)
{
    int row = blockIdx.x;
    int c = threadIdx.x * 4;
    size_t off = (size_t)row * 1024 + c;
    float4 bv = *(const float4*)(bias + c);
    float4 o = *(const float4*)(R + off);
    o.x += bv.x; o.y += bv.y; o.z += bv.z; o.w += bv.w;
    #pragma unroll
    for (int p = 0; p < P; ++p) {
        bf16x4 v = *(const bf16x4*)(parts + (size_t)p * 2048 * 1024 + off);
        o.x += (float)v[0]; o.y += (float)v[1];
        o.z += (float)v[2]; o.w += (float)v[3];
    }
    *(float4*)(out + off) = o;
}

// ---------------- fused proj-reduce + LN2 (R is bf16 xr) -------------------
__global__ __launch_bounds__(256) void reduceln_kernel(
    const bf16* __restrict__ parts, const float* __restrict__ bias,
    const bf16* __restrict__ R, const float* __restrict__ lnw,
    const float* __restrict__ lnb, float* __restrict__ out,
    bf16* __restrict__ Y)
{
    int row = blockIdx.x;
    int c = threadIdx.x * 4;
    size_t off = (size_t)row * 1024 + c;
    float4 bv = *(const float4*)(bias + c);
    bf16x4 rv = *(const bf16x4*)(R + off);
    float4 o;
    o.x = (float)rv[0] + bv.x;
    o.y = (float)rv[1] + bv.y;
    o.z = (float)rv[2] + bv.z;
    o.w = (float)rv[3] + bv.w;
    #pragma unroll
    for (int p = 0; p < 2; ++p) {
        bf16x4 v = *(const bf16x4*)(parts + (size_t)p * 2048 * 1024 + off);
        o.x += (float)v[0]; o.y += (float)v[1];
        o.z += (float)v[2]; o.w += (float)v[3];
    }
    *(float4*)(out + off) = o;
    float s  = o.x + o.y + o.z + o.w;
    float ss = o.x*o.x + o.y*o.y + o.z*o.z + o.w*o.w;
    #pragma unroll
    for (int of = 32; of > 0; of >>= 1) {
        s  += __shfl_down(s, of);
        ss += __shfl_down(ss, of);
    }
    __shared__ float rs[4], rss[4];
    int wave = threadIdx.x >> 6, lane = threadIdx.x & 63;
    if (lane == 0) { rs[wave] = s; rss[wave] = ss; }
    __syncthreads();
    s  = rs[0] + rs[1] + rs[2] + rs[3];
    ss = rss[0] + rss[1] + rss[2] + rss[3];
    float mu  = s * (1.f / 1024.f);
    float var = ss * (1.f / 1024.f) - mu * mu;
    float rstd = rsqrtf(var + 1e-5f);
    float4 wv = *(const float4*)(lnw + c);
    float4 lb = *(const float4*)(lnb + c);
    bf16 y[4];
    y[0] = (bf16)((o.x - mu) * rstd * wv.x + lb.x);
    y[1] = (bf16)((o.y - mu) * rstd * wv.y + lb.y);
    y[2] = (bf16)((o.z - mu) * rstd * wv.z + lb.z);
    y[3] = (bf16)((o.w - mu) * rstd * wv.w + lb.w);
    *(uint2*)(Y + (size_t)row * 1024 + c) = *(uint2*)y;
}

// ---------------- windowed attention v3: 16 waves/block, exp2 tables -------
__global__ __launch_bounds__(1024) void attn3_kernel(
    const bf16* __restrict__ qkv, const float* __restrict__ rel_pos,
    bf16* __restrict__ outp)
{
    __shared__ float bR[4096];   // row-major bias*log2e, swizzled 16B slots
    __shared__ float bT[4096];   // transposed
    for (int i = threadIdx.x; i < 4096; i += 1024) {
        int d = i >> 6, v = i & 63;
        float val = (d < 63 && v < 63)
                  ? rel_pos[((d + 32) % 63) * 63 + v] * 1.4426950408889634f
                  : -1e30f;
        bR[(d << 6) + (((v >> 2) ^ (d & 15)) << 2) + (v & 3)] = val;
        bT[(v << 6) + (((d >> 2) ^ (v & 15)) << 2) + (d & 3)] = val;
    }
    __syncthreads();

    const int wave = threadIdx.x >> 6;
    const int lane = threadIdx.x & 63;
    const int tk  = blockIdx.x * 16 + wave;
    const int row = tk >> 3;
    const int h   = tk & 7;
    const bf16* base = qkv + (size_t)row * 1536 + h * 63;
    float q_own = 0.f, k_own = 0.f, v_own = 0.f;
    if (lane < 63) {
        q_own = (float)base[lane] * 1.4426950408889634f;
        k_own = (float)base[504 + lane];
        v_own = (float)base[1008 + lane];
    }

    const float* myT = bT + (lane << 6);
    const int sw = lane & 15;
    float z0 = 0.f, z1 = 0.f, z2 = 0.f, z3 = 0.f;
    #pragma unroll
    for (int g = 0; g < 16; ++g) {
        f32x4 bb = *(const f32x4*)(myT + ((g ^ sw) << 2));
        z0 += __builtin_amdgcn_exp2f(fmaf(rdlane(q_own, 4*g + 0), k_own, bb[0]));
        z1 += __builtin_amdgcn_exp2f(fmaf(rdlane(q_own, 4*g + 1), k_own, bb[1]));
        z2 += __builtin_amdgcn_exp2f(fmaf(rdlane(q_own, 4*g + 2), k_own, bb[2]));
        z3 += __builtin_amdgcn_exp2f(fmaf(rdlane(q_own, 4*g + 3), k_own, bb[3]));
    }
    float Z = (z0 + z1) + (z2 + z3);
    float w_own = (lane < 63) ? v_own / Z : 0.f;

    const float* myR = bR + (lane << 6);
    float a0 = 0.f, a1 = 0.f, a2 = 0.f, a3 = 0.f;
    #pragma unroll
    for (int g = 0; g < 16; ++g) {
        f32x4 bb = *(const f32x4*)(myR + ((g ^ sw) << 2));
        a0 = fmaf(__builtin_amdgcn_exp2f(fmaf(q_own, rdlane(k_own, 4*g + 0), bb[0])),
                  rdlane(w_own, 4*g + 0), a0);
        a1 = fmaf(__builtin_amdgcn_exp2f(fmaf(q_own, rdlane(k_own, 4*g + 1), bb[1])),
                  rdlane(w_own, 4*g + 1), a1);
        a2 = fmaf(__builtin_amdgcn_exp2f(fmaf(q_own, rdlane(k_own, 4*g + 2), bb[2])),
                  rdlane(w_own, 4*g + 2), a2);
        a3 = fmaf(__builtin_amdgcn_exp2f(fmaf(q_own, rdlane(k_own, 4*g + 3), bb[3])),
                  rdlane(w_own, 4*g + 3), a3);
    }
    float acc = (a0 + a1) + (a2 + a3);

    if (lane < 63)
        outp[(size_t)row * 512 + h*63 + lane] = (bf16)acc;
    if (h == 7 && lane == 63) {
        #pragma unroll
        for (int j = 0; j < 8; ++j)
            outp[(size_t)row * 512 + 504 + j] = (bf16)0.f;
    }
}

extern "C" void kernel_launch(void* const* d_in, const int* in_sizes, int n_in,
                              void* d_out, int out_size, void* d_ws, size_t ws_size,
                              hipStream_t stream)
{
    const float* x       = (const float*)d_in[0];
    const float* ln1_w   = (const float*)d_in[1];
    const float* ln1_b   = (const float*)d_in[2];
    const float* qkv_w   = (const float*)d_in[3];
    const float* qkv_b   = (const float*)d_in[4];
    const float* rel_pos = (const float*)d_in[5];
    const float* proj_w  = (const float*)d_in[6];
    const float* proj_b  = (const float*)d_in[7];
    const float* ln2_w   = (const float*)d_in[8];
    const float* ln2_b   = (const float*)d_in[9];
    const float* fc_w    = (const float*)d_in[10];
    const float* fc_b    = (const float*)d_in[11];
    const float* cproj_w = (const float*)d_in[12];
    const float* cproj_b = (const float*)d_in[13];
    float* out = (float*)d_out;

    // ---- workspace layout (bytes) ----
    char* p = (char*)d_ws;
    bf16*  xr      = (bf16*)p;             p += (size_t)2048*1024*2;   // 4 MB
    bf16*  h_bf    = (bf16*)p;             p += (size_t)2048*1024*2;   // 4 MB
    bf16*  wqkv    = (bf16*)p;             p += (size_t)1536*1024*2;   // 3 MB
    bf16*  wproj   = (bf16*)p;             p += (size_t)1024*512*2;    // 1 MB
    bf16*  wfc     = (bf16*)p;             p += (size_t)4096*1024*2;   // 8 MB
    bf16*  wcproj  = (bf16*)p;             p += (size_t)1024*4096*2;   // 8 MB
    float* qkvb_p  = (float*)p;            p += 8192;                  // 6 KB
    bf16*  attn_bf = (bf16*)p;             p += (size_t)2048*512*2;    // 2 MB
    bf16*  qkvb    = (bf16*)p;                                         // 6 MB
    bf16*  fc_act  = (bf16*)p;             // 16 MB, overlaps qkvb (dead after attn)
    bf16*  proj_part = qkvb;               // 2 x 4 MB (dead before fc writes fc_act)
    // cproj partials: 4 x 4 MB = 16 MB at d_ws start (xr/h_bf/wqkv/wproj dead)
    bf16*  cp_part = (bf16*)d_ws;

    conv_all_kernel<<<5121, 256, 0, stream>>>(qkv_w, proj_w, fc_w, cproj_w, qkv_b,
                                              wqkv, wproj, wfc, wcproj, qkvb_p);
    rotary_ln_kernel<<<2048, 256, 0, stream>>>(x, ln1_w, ln1_b, xr, h_bf);
    // qkv: M=2048 N=1536 K=1024 -> gemm12s 12x32 = 384 WGs (12 waves/CU)
    gemm12s_kernel<0><<<dim3(12,32,1), 512, 0, stream>>>(h_bf, wqkv, qkvb_p,
                                                         qkvb, 1536, 1024, 1024);
    attn3_kernel<<<1024, 1024, 0, stream>>>(qkvb, rel_pos, attn_bf);
    // proj: M=2048 N=1024 K=512, split-K2 -> gemm12s 8x32x2 = 512 WGs
    gemm12s_kernel<3><<<dim3(8,32,2), 512, 0, stream>>>(attn_bf, wproj, nullptr,
                                                        proj_part, 1024, 512, 256);
    reduceln_kernel<<<2048, 256, 0, stream>>>(proj_part, proj_b, xr,
                                              ln2_w, ln2_b, out, h_bf);
    // fc: M=2048 N=4096 K=1024 -> gemm12 32x16 = 512 WGs (16 waves/CU)
    gemm12_kernel<1><<<dim3(32,16,1), 512, 0, stream>>>(h_bf, wfc, fc_b,
                                                        fc_act, 4096, 1024, 1024);
    // cproj: M=2048 N=1024 K=4096, split-K4 -> gemm12 8x16x4 = 512 WGs
    gemm12_kernel<3><<<dim3(8,16,4), 512, 0, stream>>>(fc_act, wcproj, nullptr,
                                                       cp_part, 1024, 4096, 1024);
    reduce_kernel<4><<<2048, 256, 0, stream>>>(cp_part, cproj_b, out, out);
}